// Round 1
// baseline (1218.803 us; speedup 1.0000x reference)
//
#include <hip/hip_runtime.h>
#include <math.h>

#define N_PTS 1024
#define BATCH 8
#define KNN 20
#define EPSB 1e-5f
#define SLOPE 0.2f

__device__ __forceinline__ float lrelu(float y) { return y > 0.f ? y : SLOPE * y; }

// ---------------- squared norms: xx[b,n] = sum_c x[b,c,n]^2 ----------------
__global__ void xx_kernel(const float* __restrict__ x, float* __restrict__ xx,
                          int C, int bstride) {
    int g = blockIdx.x * 256 + threadIdx.x;   // b*N + n
    int b = g >> 10, n = g & 1023;
    const float* xb = x + (size_t)b * bstride;
    float s = 0.f;
    for (int c = 0; c < C; c++) { float v = xb[c * N_PTS + n]; s += v * v; }
    xx[g] = s;
}

// ---------------- KNN: per (b,n) row, top-20 of -||x_n - x_m||^2 ----------------
__global__ void knn_kernel(const float* __restrict__ x, const float* __restrict__ xx,
                           int* __restrict__ idx, int C, int bstride) {
    int b = blockIdx.y;
    int n = blockIdx.x;
    int tid = threadIdx.x;
    __shared__ float dist[N_PTS];
    __shared__ float xn[128];
    __shared__ float rv[256];
    __shared__ int   ri[256];
    const float* xb = x + (size_t)b * bstride;
    for (int c = tid; c < C; c += 256) xn[c] = xb[c * N_PTS + n];
    __syncthreads();
    float xxn = xx[b * N_PTS + n];
    for (int j = 0; j < 4; j++) {
        int m = tid + j * 256;
        float acc = 0.f;
        for (int c = 0; c < C; c++) acc += xn[c] * xb[c * N_PTS + m];
        float inner = -2.0f * acc;
        dist[m] = (-xxn - inner) - xx[b * N_PTS + m];
    }
    __syncthreads();
    for (int kk = 0; kk < KNN; kk++) {
        float bv = -INFINITY; int bi = 0x7fffffff;
        for (int j = 0; j < 4; j++) {
            int m = tid + j * 256;
            float v = dist[m];
            if (v > bv || (v == bv && m < bi)) { bv = v; bi = m; }
        }
        rv[tid] = bv; ri[tid] = bi;
        __syncthreads();
        for (int s = 128; s > 0; s >>= 1) {
            if (tid < s) {
                float v2 = rv[tid + s]; int i2 = ri[tid + s];
                if (v2 > rv[tid] || (v2 == rv[tid] && i2 < ri[tid])) { rv[tid] = v2; ri[tid] = i2; }
            }
            __syncthreads();
        }
        if (tid == 0) { idx[(b * N_PTS + n) * KNN + kk] = ri[0]; dist[ri[0]] = -INFINITY; }
        __syncthreads();
    }
}

// ---------------- A = w_left * x ; Bv = (w_right - w_left) * x ----------------
__global__ void abv_kernel(const float* __restrict__ x, const float* __restrict__ w,
                           float* __restrict__ A, float* __restrict__ Bv,
                           int C, int Cout, int bstride) {
    int o = blockIdx.x;
    int b = blockIdx.y;
    int tid = threadIdx.x;
    __shared__ float wl[128], wd[128];
    for (int c = tid; c < C; c += 256) {
        float l = w[(size_t)o * 2 * C + c];
        float r = w[(size_t)o * 2 * C + C + c];
        wl[c] = l; wd[c] = r - l;
    }
    __syncthreads();
    const float* xb = x + (size_t)b * bstride;
    float* Ao = A  + ((size_t)b * Cout + o) * N_PTS;
    float* Bo = Bv + ((size_t)b * Cout + o) * N_PTS;
    for (int j = 0; j < 4; j++) {
        int n = tid + j * 256;
        float a = 0.f, bb = 0.f;
        for (int c = 0; c < C; c++) {
            float v = xb[c * N_PTS + n];
            a += wl[c] * v; bb += wd[c] * v;
        }
        Ao[n] = a; Bo[n] = bb;
    }
}

// ---------------- out[b,o,n] = lrelu(bn(max_k A[b,o,idx[n,k]] + Bv[b,o,n])) ----------------
__global__ void gmax_kernel(const float* __restrict__ A, const float* __restrict__ Bv,
                            const int* __restrict__ idx, const float* __restrict__ bnp,
                            float* __restrict__ out, int Cout, int outStrideB) {
    // grid (N/64, Cout/4, B), block 256
    int b = blockIdx.z;
    int n0 = blockIdx.x * 64;
    int o0 = blockIdx.y * 4;
    int tid = threadIdx.x;
    int nl = tid & 63, ol = tid >> 6;
    __shared__ int sidx[64 * KNN];
    for (int t = tid; t < 64 * KNN; t += 256) sidx[t] = idx[(b * N_PTS + n0) * KNN + t];
    __syncthreads();
    int o = o0 + ol;
    const float* Ao = A + ((size_t)b * Cout + o) * N_PTS;
    float best = -INFINITY;
    for (int k = 0; k < KNN; k++) {
        int j = sidx[nl * KNN + k];
        best = fmaxf(best, Ao[j]);
    }
    int n = n0 + nl;
    float pre = best + Bv[((size_t)b * Cout + o) * N_PTS + n];
    float g = bnp[o], bb = bnp[Cout + o], m = bnp[2 * Cout + o], vv = bnp[3 * Cout + o];
    float scale = g / sqrtf(vv + EPSB);
    out[(size_t)b * outStrideB + (size_t)o * N_PTS + n] = lrelu((pre - m) * scale + bb);
}

// ---------------- embedding GEMM + bn + lrelu + fused max/sum partials ----------------
__global__ void gemm6_kernel(const float* __restrict__ cat, const float* __restrict__ we,
                             const float* __restrict__ bne,
                             float* __restrict__ pmax, float* __restrict__ psum) {
    // grid (16 ntiles, 16 otiles, B); block 256 as 16x16, 4x4 microtile
    int b = blockIdx.z, ot = blockIdx.y, nt = blockIdx.x;
    int tid = threadIdx.x;
    int tx = tid & 15, ty = tid >> 4;
    __shared__ float sW[64][17];
    __shared__ float sC[16][65];
    float acc[4][4] = {};
    const float* catb = cat + (size_t)b * 512 * N_PTS;
    for (int k0 = 0; k0 < 512; k0 += 16) {
        for (int q = 0; q < 4; q++) {
            int e = tid + q * 256;
            int i = e >> 4, j = e & 15;
            sW[i][j] = we[(size_t)(ot * 64 + i) * 512 + k0 + j];
        }
        for (int q = 0; q < 4; q++) {
            int e = tid + q * 256;
            int i = e >> 6, j = e & 63;
            sC[i][j] = catb[(size_t)(k0 + i) * N_PTS + nt * 64 + j];
        }
        __syncthreads();
        for (int kk = 0; kk < 16; kk++) {
            float av[4], bv[4];
            for (int i = 0; i < 4; i++) av[i] = sW[ty * 4 + i][kk];
            for (int j = 0; j < 4; j++) bv[j] = sC[kk][tx * 4 + j];
            for (int i = 0; i < 4; i++)
                for (int j = 0; j < 4; j++) acc[i][j] += av[i] * bv[j];
        }
        __syncthreads();
    }
    __shared__ float rmax[64][16];
    __shared__ float rsum[64][16];
    for (int i = 0; i < 4; i++) {
        int o = ot * 64 + ty * 4 + i;
        float g = bne[o], bb = bne[1024 + o], m = bne[2048 + o], vv = bne[3072 + o];
        float scale = g / sqrtf(vv + EPSB);
        float mx = -INFINITY, sm = 0.f;
        for (int j = 0; j < 4; j++) {
            float y = lrelu((acc[i][j] - m) * scale + bb);
            mx = fmaxf(mx, y); sm += y;
        }
        rmax[ty * 4 + i][tx] = mx; rsum[ty * 4 + i][tx] = sm;
    }
    __syncthreads();
    if (tid < 64) {
        float mx = -INFINITY, sm = 0.f;
        for (int t = 0; t < 16; t++) { mx = fmaxf(mx, rmax[tid][t]); sm += rsum[tid][t]; }
        int o = ot * 64 + tid;
        pmax[((size_t)b * 1024 + o) * 16 + nt] = mx;
        psum[((size_t)b * 1024 + o) * 16 + nt] = sm;
    }
}

__global__ void pool_reduce_kernel(const float* __restrict__ pmax, const float* __restrict__ psum,
                                   float* __restrict__ h0) {
    int g = blockIdx.x * 256 + threadIdx.x;  // b*1024 + o
    int b = g >> 10, o = g & 1023;
    float mx = -INFINITY, sm = 0.f;
    for (int t = 0; t < 16; t++) { mx = fmaxf(mx, pmax[g * 16 + t]); sm += psum[g * 16 + t]; }
    h0[(size_t)b * 2048 + o] = mx;
    h0[(size_t)b * 2048 + 1024 + o] = sm * (1.0f / 1024.0f);
}

// ---------------- FC: one wave per output ----------------
__global__ void fc_kernel(const float* __restrict__ in, const float* __restrict__ w,
                          const float* __restrict__ bnp, const float* __restrict__ bias,
                          float* __restrict__ out, int Cin, int Cout, int mode) {
    int blk = blockIdx.x;  // b*Cout + o
    int b = blk / Cout, o = blk % Cout;
    int lane = threadIdx.x;
    const float* inb = in + (size_t)b * Cin;
    const float* wo = w + (size_t)o * Cin;
    float acc = 0.f;
    for (int c = lane; c < Cin; c += 64) acc += inb[c] * wo[c];
    for (int s = 32; s > 0; s >>= 1) acc += __shfl_down(acc, s, 64);
    if (lane == 0) {
        float y = acc;
        if (mode == 0) {
            float g = bnp[o], bb = bnp[Cout + o], m = bnp[2 * Cout + o], vv = bnp[3 * Cout + o];
            y = lrelu((y - m) * (g / sqrtf(vv + EPSB)) + bb);
        } else {
            y += bias[o];
        }
        out[(size_t)b * Cout + o] = y;
    }
}

extern "C" void kernel_launch(void* const* d_in, const int* in_sizes, int n_in,
                              void* d_out, int out_size, void* d_ws, size_t ws_size,
                              hipStream_t stream) {
    const float* x    = (const float*)d_in[0];
    const float* w0   = (const float*)d_in[1];
    const float* w1   = (const float*)d_in[2];
    const float* w2   = (const float*)d_in[3];
    const float* w3   = (const float*)d_in[4];
    const float* bn0  = (const float*)d_in[5];
    const float* bn1  = (const float*)d_in[6];
    const float* bn2  = (const float*)d_in[7];
    const float* bn3  = (const float*)d_in[8];
    const float* we   = (const float*)d_in[9];
    const float* bne  = (const float*)d_in[10];
    const float* wf0  = (const float*)d_in[11];
    const float* bnf0 = (const float*)d_in[12];
    const float* wf1  = (const float*)d_in[13];
    const float* bnf1 = (const float*)d_in[14];
    const float* wfin = (const float*)d_in[15];
    const float* bfin = (const float*)d_in[16];

    float* ws = (float*)d_ws;
    size_t off = 0;
    float* cat  = ws + off; off += (size_t)BATCH * 512 * N_PTS;   // 4,194,304
    float* A    = ws + off; off += (size_t)BATCH * 256 * N_PTS;   // 2,097,152
    float* Bv   = ws + off; off += (size_t)BATCH * 256 * N_PTS;   // 2,097,152
    float* xx   = ws + off; off += (size_t)BATCH * N_PTS;
    float* pmax = ws + off; off += (size_t)BATCH * N_PTS * 16;
    float* psum = ws + off; off += (size_t)BATCH * N_PTS * 16;
    float* h0   = ws + off; off += (size_t)BATCH * 2048;
    float* h1   = ws + off; off += (size_t)BATCH * 512;
    float* h2   = ws + off; off += (size_t)BATCH * 256;
    int*   idx  = (int*)(ws + off);

    const int CSTR = 512 * N_PTS;   // cat batch stride

    // ---- block 0: input x (B,3,N), out -> cat ch [0,64)
    xx_kernel<<<32, 256, 0, stream>>>(x, xx, 3, 3 * N_PTS);
    knn_kernel<<<dim3(N_PTS, BATCH), 256, 0, stream>>>(x, xx, idx, 3, 3 * N_PTS);
    abv_kernel<<<dim3(64, BATCH), 256, 0, stream>>>(x, w0, A, Bv, 3, 64, 3 * N_PTS);
    gmax_kernel<<<dim3(16, 16, BATCH), 256, 0, stream>>>(A, Bv, idx, bn0, cat, 64, CSTR);

    // ---- block 1: input cat ch [0,64), out -> ch [64,128)
    xx_kernel<<<32, 256, 0, stream>>>(cat, xx, 64, CSTR);
    knn_kernel<<<dim3(N_PTS, BATCH), 256, 0, stream>>>(cat, xx, idx, 64, CSTR);
    abv_kernel<<<dim3(64, BATCH), 256, 0, stream>>>(cat, w1, A, Bv, 64, 64, CSTR);
    gmax_kernel<<<dim3(16, 16, BATCH), 256, 0, stream>>>(A, Bv, idx, bn1, cat + 64 * N_PTS, 64, CSTR);

    // ---- block 2: input ch [64,128), out -> ch [128,256)
    xx_kernel<<<32, 256, 0, stream>>>(cat + 64 * N_PTS, xx, 64, CSTR);
    knn_kernel<<<dim3(N_PTS, BATCH), 256, 0, stream>>>(cat + 64 * N_PTS, xx, idx, 64, CSTR);
    abv_kernel<<<dim3(128, BATCH), 256, 0, stream>>>(cat + 64 * N_PTS, w2, A, Bv, 64, 128, CSTR);
    gmax_kernel<<<dim3(16, 32, BATCH), 256, 0, stream>>>(A, Bv, idx, bn2, cat + 128 * N_PTS, 128, CSTR);

    // ---- block 3: input ch [128,256), out -> ch [256,512)
    xx_kernel<<<32, 256, 0, stream>>>(cat + 128 * N_PTS, xx, 128, CSTR);
    knn_kernel<<<dim3(N_PTS, BATCH), 256, 0, stream>>>(cat + 128 * N_PTS, xx, idx, 128, CSTR);
    abv_kernel<<<dim3(256, BATCH), 256, 0, stream>>>(cat + 128 * N_PTS, w3, A, Bv, 128, 256, CSTR);
    gmax_kernel<<<dim3(16, 64, BATCH), 256, 0, stream>>>(A, Bv, idx, bn3, cat + 256 * N_PTS, 256, CSTR);

    // ---- embedding + pooling
    gemm6_kernel<<<dim3(16, 16, BATCH), 256, 0, stream>>>(cat, we, bne, pmax, psum);
    pool_reduce_kernel<<<32, 256, 0, stream>>>(pmax, psum, h0);

    // ---- FC head
    fc_kernel<<<BATCH * 512, 64, 0, stream>>>(h0, wf0, bnf0, nullptr, h1, 2048, 512, 0);
    fc_kernel<<<BATCH * 256, 64, 0, stream>>>(h1, wf1, bnf1, nullptr, h2, 512, 256, 0);
    fc_kernel<<<BATCH * 64, 64, 0, stream>>>(h2, wfin, nullptr, bfin, (float*)d_out, 256, 64, 1);
}

// Round 2
// 776.516 us; speedup vs baseline: 1.5696x; 1.5696x over previous
//
#include <hip/hip_runtime.h>
#include <math.h>

#define N_PTS 1024
#define BATCH 8
#define KNN 20
#define EPSB 1e-5f
#define SLOPE 0.2f

__device__ __forceinline__ float lrelu(float y) { return y > 0.f ? y : SLOPE * y; }

// ---------------- squared norms: xx[b,n] = sum_c x[b,c,n]^2 ----------------
__global__ void xx_kernel(const float* __restrict__ x, float* __restrict__ xx,
                          int C, int bstride) {
    int g = blockIdx.x * 256 + threadIdx.x;   // b*N + n
    int b = g >> 10, n = g & 1023;
    const float* xb = x + (size_t)b * bstride;
    float s = 0.f;
    for (int c = 0; c < C; c++) { float v = xb[c * N_PTS + n]; s += v * v; }
    xx[g] = s;
}

// ---------------- pd[b,n,m] = 2*dot(x_n,x_m) - xx[n] - xx[m] ----------------
// 64x64 tile per block, 256 threads as 16x16, 4x4 microtile.
__global__ void pd_kernel(const float* __restrict__ x, const float* __restrict__ xx,
                          float* __restrict__ pd, int C, int bstride) {
    int b = blockIdx.z;
    int m0 = blockIdx.x * 64;
    int n0 = blockIdx.y * 64;
    int tid = threadIdx.x;
    int tx = tid & 15, ty = tid >> 4;
    __shared__ float sN[16][64];   // [k][n-local]; stride 64 keeps float4 16B-aligned,
    __shared__ float sM[16][64];   // reads are <=2-way bank aliased (free on gfx950)
    const float* xb = x + (size_t)b * bstride;
    float acc[4][4] = {};
    for (int c0 = 0; c0 < C; c0 += 16) {
        for (int q = 0; q < 4; q++) {
            int e = tid + q * 256;
            int k = e >> 6, j = e & 63;
            int c = c0 + k;
            float vn = (c < C) ? xb[(size_t)c * N_PTS + n0 + j] : 0.f;
            float vm = (c < C) ? xb[(size_t)c * N_PTS + m0 + j] : 0.f;
            sN[k][j] = vn;
            sM[k][j] = vm;
        }
        __syncthreads();
        for (int k = 0; k < 16; k++) {
            float4 a4 = *(const float4*)&sN[k][ty * 4];
            float4 b4 = *(const float4*)&sM[k][tx * 4];
            float av[4] = {a4.x, a4.y, a4.z, a4.w};
            float bv[4] = {b4.x, b4.y, b4.z, b4.w};
            for (int i = 0; i < 4; i++)
                for (int j = 0; j < 4; j++) acc[i][j] += av[i] * bv[j];
        }
        __syncthreads();
    }
    float xn[4], xm[4];
    for (int i = 0; i < 4; i++) xn[i] = xx[b * N_PTS + n0 + ty * 4 + i];
    for (int j = 0; j < 4; j++) xm[j] = xx[b * N_PTS + m0 + tx * 4 + j];
    for (int i = 0; i < 4; i++) {
        float4 o;
        o.x = 2.f * acc[i][0] - xn[i] - xm[0];
        o.y = 2.f * acc[i][1] - xn[i] - xm[1];
        o.z = 2.f * acc[i][2] - xn[i] - xm[2];
        o.w = 2.f * acc[i][3] - xn[i] - xm[3];
        *(float4*)&pd[((size_t)(b * N_PTS + n0 + ty * 4 + i)) * N_PTS + m0 + tx * 4] = o;
    }
}

// ---------------- top-20 per row, one wave per row, barrier-free ----------------
__global__ void topk_kernel(const float* __restrict__ pd, int* __restrict__ idx) {
    int row = blockIdx.x * 4 + (threadIdx.x >> 6);   // row = b*N + n
    int lane = threadIdx.x & 63;
    const float* p = pd + (size_t)row * N_PTS;
    float v[16];
    for (int q = 0; q < 4; q++) {
        float4 t = *(const float4*)&p[lane * 16 + q * 4];
        v[q * 4 + 0] = t.x; v[q * 4 + 1] = t.y; v[q * 4 + 2] = t.z; v[q * 4 + 3] = t.w;
    }
    for (int kk = 0; kk < KNN; kk++) {
        // local argmax (ties keep lowest j -> lowest global index for this lane)
        float bv = v[0]; int bj = 0;
        for (int j = 1; j < 16; j++) if (v[j] > bv) { bv = v[j]; bj = j; }
        int bi = lane * 16 + bj;
        // wave argmax; tie -> lower index (matches lax.top_k)
        for (int s = 32; s > 0; s >>= 1) {
            float ov = __shfl_down(bv, s, 64);
            int oi = __shfl_down(bi, s, 64);
            if (ov > bv || (ov == bv && oi < bi)) { bv = ov; bi = oi; }
        }
        bi = __shfl(bi, 0, 64);
        if ((bi >> 4) == lane) v[bi & 15] = -INFINITY;
        if (lane == 0) idx[row * KNN + kk] = bi;
    }
}

// ---------------- A = w_left * x ; Bv = (w_right - w_left) * x ----------------
__global__ void abv_kernel(const float* __restrict__ x, const float* __restrict__ w,
                           float* __restrict__ A, float* __restrict__ Bv,
                           int C, int Cout, int bstride) {
    int o = blockIdx.x;
    int b = blockIdx.y;
    int tid = threadIdx.x;
    __shared__ float wl[128], wd[128];
    for (int c = tid; c < C; c += 256) {
        float l = w[(size_t)o * 2 * C + c];
        float r = w[(size_t)o * 2 * C + C + c];
        wl[c] = l; wd[c] = r - l;
    }
    __syncthreads();
    const float* xb = x + (size_t)b * bstride;
    float* Ao = A  + ((size_t)b * Cout + o) * N_PTS;
    float* Bo = Bv + ((size_t)b * Cout + o) * N_PTS;
    for (int j = 0; j < 4; j++) {
        int n = tid + j * 256;
        float a = 0.f, bb = 0.f;
        for (int c = 0; c < C; c++) {
            float v = xb[c * N_PTS + n];
            a += wl[c] * v; bb += wd[c] * v;
        }
        Ao[n] = a; Bo[n] = bb;
    }
}

// ---------------- out[b,o,n] = lrelu(bn(max_k A[b,o,idx[n,k]] + Bv[b,o,n])) ----------------
__global__ void gmax_kernel(const float* __restrict__ A, const float* __restrict__ Bv,
                            const int* __restrict__ idx, const float* __restrict__ bnp,
                            float* __restrict__ out, int Cout, int outStrideB) {
    // grid (N/64, Cout/4, B), block 256
    int b = blockIdx.z;
    int n0 = blockIdx.x * 64;
    int o0 = blockIdx.y * 4;
    int tid = threadIdx.x;
    int nl = tid & 63, ol = tid >> 6;
    __shared__ int sidx[64 * KNN];
    for (int t = tid; t < 64 * KNN; t += 256) sidx[t] = idx[(b * N_PTS + n0) * KNN + t];
    __syncthreads();
    int o = o0 + ol;
    const float* Ao = A + ((size_t)b * Cout + o) * N_PTS;
    float best = -INFINITY;
    for (int k = 0; k < KNN; k++) {
        int j = sidx[nl * KNN + k];
        best = fmaxf(best, Ao[j]);
    }
    int n = n0 + nl;
    float pre = best + Bv[((size_t)b * Cout + o) * N_PTS + n];
    float g = bnp[o], bb = bnp[Cout + o], m = bnp[2 * Cout + o], vv = bnp[3 * Cout + o];
    float scale = g / sqrtf(vv + EPSB);
    out[(size_t)b * outStrideB + (size_t)o * N_PTS + n] = lrelu((pre - m) * scale + bb);
}

// ---------------- embedding GEMM + bn + lrelu + fused max/sum partials ----------------
__global__ void gemm6_kernel(const float* __restrict__ cat, const float* __restrict__ we,
                             const float* __restrict__ bne,
                             float* __restrict__ pmax, float* __restrict__ psum) {
    // grid (16 ntiles, 16 otiles, B); block 256 as 16x16, 4x4 microtile
    int b = blockIdx.z, ot = blockIdx.y, nt = blockIdx.x;
    int tid = threadIdx.x;
    int tx = tid & 15, ty = tid >> 4;
    __shared__ float sW[64][17];
    __shared__ float sC[16][65];
    float acc[4][4] = {};
    const float* catb = cat + (size_t)b * 512 * N_PTS;
    for (int k0 = 0; k0 < 512; k0 += 16) {
        for (int q = 0; q < 4; q++) {
            int e = tid + q * 256;
            int i = e >> 4, j = e & 15;
            sW[i][j] = we[(size_t)(ot * 64 + i) * 512 + k0 + j];
        }
        for (int q = 0; q < 4; q++) {
            int e = tid + q * 256;
            int i = e >> 6, j = e & 63;
            sC[i][j] = catb[(size_t)(k0 + i) * N_PTS + nt * 64 + j];
        }
        __syncthreads();
        for (int kk = 0; kk < 16; kk++) {
            float av[4], bv[4];
            for (int i = 0; i < 4; i++) av[i] = sW[ty * 4 + i][kk];
            for (int j = 0; j < 4; j++) bv[j] = sC[kk][tx * 4 + j];
            for (int i = 0; i < 4; i++)
                for (int j = 0; j < 4; j++) acc[i][j] += av[i] * bv[j];
        }
        __syncthreads();
    }
    __shared__ float rmax[64][16];
    __shared__ float rsum[64][16];
    for (int i = 0; i < 4; i++) {
        int o = ot * 64 + ty * 4 + i;
        float g = bne[o], bb = bne[1024 + o], m = bne[2048 + o], vv = bne[3072 + o];
        float scale = g / sqrtf(vv + EPSB);
        float mx = -INFINITY, sm = 0.f;
        for (int j = 0; j < 4; j++) {
            float y = lrelu((acc[i][j] - m) * scale + bb);
            mx = fmaxf(mx, y); sm += y;
        }
        rmax[ty * 4 + i][tx] = mx; rsum[ty * 4 + i][tx] = sm;
    }
    __syncthreads();
    if (tid < 64) {
        float mx = -INFINITY, sm = 0.f;
        for (int t = 0; t < 16; t++) { mx = fmaxf(mx, rmax[tid][t]); sm += rsum[tid][t]; }
        int o = ot * 64 + tid;
        pmax[((size_t)b * 1024 + o) * 16 + nt] = mx;
        psum[((size_t)b * 1024 + o) * 16 + nt] = sm;
    }
}

__global__ void pool_reduce_kernel(const float* __restrict__ pmax, const float* __restrict__ psum,
                                   float* __restrict__ h0) {
    int g = blockIdx.x * 256 + threadIdx.x;  // b*1024 + o
    int b = g >> 10, o = g & 1023;
    float mx = -INFINITY, sm = 0.f;
    for (int t = 0; t < 16; t++) { mx = fmaxf(mx, pmax[g * 16 + t]); sm += psum[g * 16 + t]; }
    h0[(size_t)b * 2048 + o] = mx;
    h0[(size_t)b * 2048 + 1024 + o] = sm * (1.0f / 1024.0f);
}

// ---------------- FC: one wave per output ----------------
__global__ void fc_kernel(const float* __restrict__ in, const float* __restrict__ w,
                          const float* __restrict__ bnp, const float* __restrict__ bias,
                          float* __restrict__ out, int Cin, int Cout, int mode) {
    int blk = blockIdx.x;  // b*Cout + o
    int b = blk / Cout, o = blk % Cout;
    int lane = threadIdx.x;
    const float* inb = in + (size_t)b * Cin;
    const float* wo = w + (size_t)o * Cin;
    float acc = 0.f;
    for (int c = lane; c < Cin; c += 64) acc += inb[c] * wo[c];
    for (int s = 32; s > 0; s >>= 1) acc += __shfl_down(acc, s, 64);
    if (lane == 0) {
        float y = acc;
        if (mode == 0) {
            float g = bnp[o], bb = bnp[Cout + o], m = bnp[2 * Cout + o], vv = bnp[3 * Cout + o];
            y = lrelu((y - m) * (g / sqrtf(vv + EPSB)) + bb);
        } else {
            y += bias[o];
        }
        out[(size_t)b * Cout + o] = y;
    }
}

extern "C" void kernel_launch(void* const* d_in, const int* in_sizes, int n_in,
                              void* d_out, int out_size, void* d_ws, size_t ws_size,
                              hipStream_t stream) {
    const float* x    = (const float*)d_in[0];
    const float* w0   = (const float*)d_in[1];
    const float* w1   = (const float*)d_in[2];
    const float* w2   = (const float*)d_in[3];
    const float* w3   = (const float*)d_in[4];
    const float* bn0  = (const float*)d_in[5];
    const float* bn1  = (const float*)d_in[6];
    const float* bn2  = (const float*)d_in[7];
    const float* bn3  = (const float*)d_in[8];
    const float* we   = (const float*)d_in[9];
    const float* bne  = (const float*)d_in[10];
    const float* wf0  = (const float*)d_in[11];
    const float* bnf0 = (const float*)d_in[12];
    const float* wf1  = (const float*)d_in[13];
    const float* bnf1 = (const float*)d_in[14];
    const float* wfin = (const float*)d_in[15];
    const float* bfin = (const float*)d_in[16];

    float* ws = (float*)d_ws;
    size_t off = 0;
    float* cat  = ws + off; off += (size_t)BATCH * 512 * N_PTS;        // 16 MB
    // Union region U: pd (B*N*N floats) overlaps A and Bv — lifetimes are
    // disjoint in stream order (pd dead after topk; A/Bv written after topk,
    // dead after gmax which precedes next layer's pd).
    float* U    = ws + off; off += (size_t)BATCH * N_PTS * N_PTS;      // 33.5 MB
    float* pd   = U;
    float* A    = U;
    float* Bv   = U + (size_t)BATCH * 256 * N_PTS;
    float* xx   = ws + off; off += (size_t)BATCH * N_PTS;
    float* pmax = ws + off; off += (size_t)BATCH * N_PTS * 16;
    float* psum = ws + off; off += (size_t)BATCH * N_PTS * 16;
    float* h0   = ws + off; off += (size_t)BATCH * 2048;
    float* h1   = ws + off; off += (size_t)BATCH * 512;
    float* h2   = ws + off; off += (size_t)BATCH * 256;
    int*   idx  = (int*)(ws + off);

    const int CSTR = 512 * N_PTS;   // cat batch stride
    const dim3 pdGrid(16, 16, BATCH);
    const int  topkBlocks = BATCH * N_PTS / 4;

    // ---- block 0: input x (B,3,N), out -> cat ch [0,64)
    xx_kernel<<<32, 256, 0, stream>>>(x, xx, 3, 3 * N_PTS);
    pd_kernel<<<pdGrid, 256, 0, stream>>>(x, xx, pd, 3, 3 * N_PTS);
    topk_kernel<<<topkBlocks, 256, 0, stream>>>(pd, idx);
    abv_kernel<<<dim3(64, BATCH), 256, 0, stream>>>(x, w0, A, Bv, 3, 64, 3 * N_PTS);
    gmax_kernel<<<dim3(16, 16, BATCH), 256, 0, stream>>>(A, Bv, idx, bn0, cat, 64, CSTR);

    // ---- block 1: input cat ch [0,64), out -> ch [64,128)
    xx_kernel<<<32, 256, 0, stream>>>(cat, xx, 64, CSTR);
    pd_kernel<<<pdGrid, 256, 0, stream>>>(cat, xx, pd, 64, CSTR);
    topk_kernel<<<topkBlocks, 256, 0, stream>>>(pd, idx);
    abv_kernel<<<dim3(64, BATCH), 256, 0, stream>>>(cat, w1, A, Bv, 64, 64, CSTR);
    gmax_kernel<<<dim3(16, 16, BATCH), 256, 0, stream>>>(A, Bv, idx, bn1, cat + 64 * N_PTS, 64, CSTR);

    // ---- block 2: input ch [64,128), out -> ch [128,256)
    xx_kernel<<<32, 256, 0, stream>>>(cat + 64 * N_PTS, xx, 64, CSTR);
    pd_kernel<<<pdGrid, 256, 0, stream>>>(cat + 64 * N_PTS, xx, pd, 64, CSTR);
    topk_kernel<<<topkBlocks, 256, 0, stream>>>(pd, idx);
    abv_kernel<<<dim3(128, BATCH), 256, 0, stream>>>(cat + 64 * N_PTS, w2, A, Bv, 64, 128, CSTR);
    gmax_kernel<<<dim3(16, 32, BATCH), 256, 0, stream>>>(A, Bv, idx, bn2, cat + 128 * N_PTS, 128, CSTR);

    // ---- block 3: input ch [128,256), out -> ch [256,512)
    xx_kernel<<<32, 256, 0, stream>>>(cat + 128 * N_PTS, xx, 128, CSTR);
    pd_kernel<<<pdGrid, 256, 0, stream>>>(cat + 128 * N_PTS, xx, pd, 128, CSTR);
    topk_kernel<<<topkBlocks, 256, 0, stream>>>(pd, idx);
    abv_kernel<<<dim3(256, BATCH), 256, 0, stream>>>(cat + 128 * N_PTS, w3, A, Bv, 128, 256, CSTR);
    gmax_kernel<<<dim3(16, 64, BATCH), 256, 0, stream>>>(A, Bv, idx, bn3, cat + 256 * N_PTS, 256, CSTR);

    // ---- embedding + pooling
    gemm6_kernel<<<dim3(16, 16, BATCH), 256, 0, stream>>>(cat, we, bne, pmax, psum);
    pool_reduce_kernel<<<32, 256, 0, stream>>>(pmax, psum, h0);

    // ---- FC head
    fc_kernel<<<BATCH * 512, 64, 0, stream>>>(h0, wf0, bnf0, nullptr, h1, 2048, 512, 0);
    fc_kernel<<<BATCH * 256, 64, 0, stream>>>(h1, wf1, bnf1, nullptr, h2, 512, 256, 0);
    fc_kernel<<<BATCH * 64, 64, 0, stream>>>(h2, wfin, nullptr, bfin, (float*)d_out, 256, 64, 1);
}

// Round 3
// 637.125 us; speedup vs baseline: 1.9130x; 1.2188x over previous
//
#include <hip/hip_runtime.h>
#include <math.h>

#define N_PTS 1024
#define BATCH 8
#define KNN 20
#define EPSB 1e-5f
#define SLOPE 0.2f

typedef __attribute__((ext_vector_type(8))) short short8;
typedef __attribute__((ext_vector_type(4))) float f32x4;
typedef unsigned short ushort_t;

__device__ __forceinline__ float lrelu(float y) { return y > 0.f ? y : SLOPE * y; }

__device__ __forceinline__ ushort_t f2bf(float f) {
    union { float f; unsigned u; } v; v.f = f;
    unsigned r = v.u + 0x7FFF + ((v.u >> 16) & 1);   // RNE
    return (ushort_t)(r >> 16);
}

// ---------------- squared norms: xx[b,n] = sum_c x[b,c,n]^2 ----------------
__global__ void xx_kernel(const float* __restrict__ x, float* __restrict__ xx,
                          int C, int bstride) {
    int g = blockIdx.x * 256 + threadIdx.x;   // b*N + n
    int b = g >> 10, n = g & 1023;
    const float* xb = x + (size_t)b * bstride;
    float s = 0.f;
    for (int c = 0; c < C; c++) { float v = xb[c * N_PTS + n]; s += v * v; }
    xx[g] = s;
}

// ---------------- pd[b,n,m] = 2*dot(x_n,x_m) - xx[n] - xx[m] ----------------
__global__ void pd_kernel(const float* __restrict__ x, const float* __restrict__ xx,
                          float* __restrict__ pd, int C, int bstride) {
    int b = blockIdx.z;
    int m0 = blockIdx.x * 64;
    int n0 = blockIdx.y * 64;
    int tid = threadIdx.x;
    int tx = tid & 15, ty = tid >> 4;
    __shared__ float sN[16][64];
    __shared__ float sM[16][64];
    const float* xb = x + (size_t)b * bstride;
    float acc[4][4] = {};
    for (int c0 = 0; c0 < C; c0 += 16) {
        for (int q = 0; q < 4; q++) {
            int e = tid + q * 256;
            int k = e >> 6, j = e & 63;
            int c = c0 + k;
            float vn = (c < C) ? xb[(size_t)c * N_PTS + n0 + j] : 0.f;
            float vm = (c < C) ? xb[(size_t)c * N_PTS + m0 + j] : 0.f;
            sN[k][j] = vn;
            sM[k][j] = vm;
        }
        __syncthreads();
        for (int k = 0; k < 16; k++) {
            float4 a4 = *(const float4*)&sN[k][ty * 4];
            float4 b4 = *(const float4*)&sM[k][tx * 4];
            float av[4] = {a4.x, a4.y, a4.z, a4.w};
            float bv[4] = {b4.x, b4.y, b4.z, b4.w};
            for (int i = 0; i < 4; i++)
                for (int j = 0; j < 4; j++) acc[i][j] += av[i] * bv[j];
        }
        __syncthreads();
    }
    float xn[4], xm[4];
    for (int i = 0; i < 4; i++) xn[i] = xx[b * N_PTS + n0 + ty * 4 + i];
    for (int j = 0; j < 4; j++) xm[j] = xx[b * N_PTS + m0 + tx * 4 + j];
    for (int i = 0; i < 4; i++) {
        float4 o;
        o.x = 2.f * acc[i][0] - xn[i] - xm[0];
        o.y = 2.f * acc[i][1] - xn[i] - xm[1];
        o.z = 2.f * acc[i][2] - xn[i] - xm[2];
        o.w = 2.f * acc[i][3] - xn[i] - xm[3];
        *(float4*)&pd[((size_t)(b * N_PTS + n0 + ty * 4 + i)) * N_PTS + m0 + tx * 4] = o;
    }
}

// ---------------- top-20 per row, one wave per row, barrier-free ----------------
__global__ void topk_kernel(const float* __restrict__ pd, int* __restrict__ idx) {
    int row = blockIdx.x * 4 + (threadIdx.x >> 6);   // row = b*N + n
    int lane = threadIdx.x & 63;
    const float* p = pd + (size_t)row * N_PTS;
    float v[16];
    for (int q = 0; q < 4; q++) {
        float4 t = *(const float4*)&p[lane * 16 + q * 4];
        v[q * 4 + 0] = t.x; v[q * 4 + 1] = t.y; v[q * 4 + 2] = t.z; v[q * 4 + 3] = t.w;
    }
    for (int kk = 0; kk < KNN; kk++) {
        float bv = v[0]; int bj = 0;
        for (int j = 1; j < 16; j++) if (v[j] > bv) { bv = v[j]; bj = j; }
        int bi = lane * 16 + bj;
        for (int s = 32; s > 0; s >>= 1) {
            float ov = __shfl_down(bv, s, 64);
            int oi = __shfl_down(bi, s, 64);
            if (ov > bv || (ov == bv && oi < bi)) { bv = ov; bi = oi; }
        }
        bi = __shfl(bi, 0, 64);
        if ((bi >> 4) == lane) v[bi & 15] = -INFINITY;
        if (lane == 0) idx[row * KNN + kk] = bi;
    }
}

// ---------------- A = w_left * x ; Bv = (w_right - w_left) * x ----------------
__global__ void abv_kernel(const float* __restrict__ x, const float* __restrict__ w,
                           float* __restrict__ A, float* __restrict__ Bv,
                           int C, int Cout, int bstride) {
    int o = blockIdx.x;
    int b = blockIdx.y;
    int tid = threadIdx.x;
    __shared__ float wl[128], wd[128];
    for (int c = tid; c < C; c += 256) {
        float l = w[(size_t)o * 2 * C + c];
        float r = w[(size_t)o * 2 * C + C + c];
        wl[c] = l; wd[c] = r - l;
    }
    __syncthreads();
    const float* xb = x + (size_t)b * bstride;
    float* Ao = A  + ((size_t)b * Cout + o) * N_PTS;
    float* Bo = Bv + ((size_t)b * Cout + o) * N_PTS;
    for (int j = 0; j < 4; j++) {
        int n = tid + j * 256;
        float a = 0.f, bb = 0.f;
        for (int c = 0; c < C; c++) {
            float v = xb[c * N_PTS + n];
            a += wl[c] * v; bb += wd[c] * v;
        }
        Ao[n] = a; Bo[n] = bb;
    }
}

// ---------------- out[b,o,n] = lrelu(bn(max_k A[b,o,idx[n,k]] + Bv[b,o,n])) ----------------
__global__ void gmax_kernel(const float* __restrict__ A, const float* __restrict__ Bv,
                            const int* __restrict__ idx, const float* __restrict__ bnp,
                            float* __restrict__ out, int Cout, int outStrideB) {
    int b = blockIdx.z;
    int n0 = blockIdx.x * 64;
    int o0 = blockIdx.y * 4;
    int tid = threadIdx.x;
    int nl = tid & 63, ol = tid >> 6;
    __shared__ int sidx[64 * KNN];
    for (int t = tid; t < 64 * KNN; t += 256) sidx[t] = idx[(b * N_PTS + n0) * KNN + t];
    __syncthreads();
    int o = o0 + ol;
    const float* Ao = A + ((size_t)b * Cout + o) * N_PTS;
    float best = -INFINITY;
    for (int k = 0; k < KNN; k++) {
        int j = sidx[nl * KNN + k];
        best = fmaxf(best, Ao[j]);
    }
    int n = n0 + nl;
    float pre = best + Bv[((size_t)b * Cout + o) * N_PTS + n];
    float g = bnp[o], bb = bnp[Cout + o], m = bnp[2 * Cout + o], vv = bnp[3 * Cout + o];
    float scale = g / sqrtf(vv + EPSB);
    out[(size_t)b * outStrideB + (size_t)o * N_PTS + n] = lrelu((pre - m) * scale + bb);
}

// ---------------- we fp32 -> bf16 ----------------
__global__ void wconv_kernel(const float* __restrict__ w, ushort_t* __restrict__ wh) {
    int g = blockIdx.x * 256 + threadIdx.x;       // element-group of 4
    float4 v = ((const float4*)w)[g];
    ushort4 o;
    o.x = f2bf(v.x); o.y = f2bf(v.y); o.z = f2bf(v.z); o.w = f2bf(v.w);
    ((ushort4*)wh)[g] = o;
}

// ---------------- cat fp32 [b][c][n] -> catT bf16 [b][n][c] ----------------
__global__ void catT_kernel(const float* __restrict__ cat, ushort_t* __restrict__ catT) {
    // grid (16 n-tiles, 8 c-tiles, B), block 256
    int b = blockIdx.z, ct = blockIdx.y, nt = blockIdx.x;
    int tid = threadIdx.x;
    __shared__ float tile[64][65];
    const float* cb = cat + (size_t)b * 512 * N_PTS;
    for (int q = 0; q < 16; q++) {
        int e = q * 256 + tid;
        int c = e >> 6, n = e & 63;
        tile[c][n] = cb[(size_t)(ct * 64 + c) * N_PTS + nt * 64 + n];
    }
    __syncthreads();
    for (int q = 0; q < 16; q++) {
        int e = q * 256 + tid;
        int n = e >> 6, c = e & 63;
        catT[((size_t)b * N_PTS + nt * 64 + n) * 512 + ct * 64 + c] = f2bf(tile[c][n]);
    }
}

// ---------------- embedding GEMM (bf16 MFMA) + bn + lrelu + fused max/sum ----------------
__global__ void __launch_bounds__(256)
gemm6_mfma(const ushort_t* __restrict__ weh, const ushort_t* __restrict__ catT,
           const float* __restrict__ bne,
           float* __restrict__ pmax, float* __restrict__ psum) {
    // grid (8 ntiles, 8 otiles, B); 256 thr = 4 waves; 128x128 tile, BK=32
    int b = blockIdx.z, ot = blockIdx.y, nt = blockIdx.x;
    int tid = threadIdx.x;
    int w = tid >> 6, lane = tid & 63, q = lane >> 4, lr = lane & 15;
    int mblk = w >> 1, nblk = w & 1;
    __shared__ __align__(16) ushort_t sA[128 * 40];  // row stride 40 shorts: balanced banks
    __shared__ __align__(16) ushort_t sB[128 * 40];
    __shared__ float sa[128], sc[128];
    __shared__ float redmax[128][2], redsum[128][2];
    int o0 = ot * 128, n0 = nt * 128;
    if (tid < 128) {
        int o = o0 + tid;
        float g = bne[o], bb = bne[1024 + o], m = bne[2048 + o], vv = bne[3072 + o];
        float scale = g / sqrtf(vv + EPSB);
        sa[tid] = scale; sc[tid] = bb - m * scale;
    }
    f32x4 acc[4][4] = {};
    const ushort_t* cT = catT + (size_t)b * N_PTS * 512;
    int r0 = tid >> 2, s = tid & 3;
    for (int k0 = 0; k0 < 512; k0 += 32) {
        __syncthreads();
        for (int h = 0; h < 2; h++) {
            int r = r0 + h * 64;
            *(short8*)&sA[r * 40 + s * 8] = *(const short8*)(weh + (size_t)(o0 + r) * 512 + k0 + s * 8);
            *(short8*)&sB[r * 40 + s * 8] = *(const short8*)(cT  + (size_t)(n0 + r) * 512 + k0 + s * 8);
        }
        __syncthreads();
        short8 af[4], bfr[4];
        for (int mi = 0; mi < 4; mi++)
            af[mi] = *(const short8*)&sA[(mblk * 64 + mi * 16 + lr) * 40 + q * 8];
        for (int ni = 0; ni < 4; ni++)
            bfr[ni] = *(const short8*)&sB[(nblk * 64 + ni * 16 + lr) * 40 + q * 8];
        for (int mi = 0; mi < 4; mi++)
            for (int ni = 0; ni < 4; ni++)
                acc[mi][ni] = __builtin_amdgcn_mfma_f32_16x16x32_bf16(af[mi], bfr[ni], acc[mi][ni], 0, 0, 0);
    }
    // epilogue: D[m = mblk*64+mi*16+q*4+r][n = nblk*64+ni*16+lr]
    for (int mi = 0; mi < 4; mi++) {
        for (int r = 0; r < 4; r++) {
            int row = mblk * 64 + mi * 16 + q * 4 + r;
            float a = sa[row], c = sc[row];
            float mx = -INFINITY, sm = 0.f;
            for (int ni = 0; ni < 4; ni++) {
                float y = lrelu(acc[mi][ni][r] * a + c);
                mx = fmaxf(mx, y); sm += y;
            }
            for (int msk = 1; msk < 16; msk <<= 1) {
                mx = fmaxf(mx, __shfl_xor(mx, msk, 16));
                sm += __shfl_xor(sm, msk, 16);
            }
            if (lr == 0) { redmax[row][nblk] = mx; redsum[row][nblk] = sm; }
        }
    }
    __syncthreads();
    if (tid < 128) {
        float mx = fmaxf(redmax[tid][0], redmax[tid][1]);
        float sm = redsum[tid][0] + redsum[tid][1];
        int o = o0 + tid;
        pmax[((size_t)(b * 1024 + o)) * 8 + nt] = mx;
        psum[((size_t)(b * 1024 + o)) * 8 + nt] = sm;
    }
}

__global__ void pool_reduce_kernel(const float* __restrict__ pmax, const float* __restrict__ psum,
                                   float* __restrict__ h0) {
    int g = blockIdx.x * 256 + threadIdx.x;  // b*1024 + o
    int b = g >> 10, o = g & 1023;
    float mx = -INFINITY, sm = 0.f;
    for (int t = 0; t < 8; t++) { mx = fmaxf(mx, pmax[g * 8 + t]); sm += psum[g * 8 + t]; }
    h0[(size_t)b * 2048 + o] = mx;
    h0[(size_t)b * 2048 + 1024 + o] = sm * (1.0f / 1024.0f);
}

// ---------------- FC: one wave per output ----------------
__global__ void fc_kernel(const float* __restrict__ in, const float* __restrict__ w,
                          const float* __restrict__ bnp, const float* __restrict__ bias,
                          float* __restrict__ out, int Cin, int Cout, int mode) {
    int blk = blockIdx.x;  // b*Cout + o
    int b = blk / Cout, o = blk % Cout;
    int lane = threadIdx.x;
    const float* inb = in + (size_t)b * Cin;
    const float* wo = w + (size_t)o * Cin;
    float acc = 0.f;
    for (int c = lane; c < Cin; c += 64) acc += inb[c] * wo[c];
    for (int s = 32; s > 0; s >>= 1) acc += __shfl_down(acc, s, 64);
    if (lane == 0) {
        float y = acc;
        if (mode == 0) {
            float g = bnp[o], bb = bnp[Cout + o], m = bnp[2 * Cout + o], vv = bnp[3 * Cout + o];
            y = lrelu((y - m) * (g / sqrtf(vv + EPSB)) + bb);
        } else {
            y += bias[o];
        }
        out[(size_t)b * Cout + o] = y;
    }
}

extern "C" void kernel_launch(void* const* d_in, const int* in_sizes, int n_in,
                              void* d_out, int out_size, void* d_ws, size_t ws_size,
                              hipStream_t stream) {
    const float* x    = (const float*)d_in[0];
    const float* w0   = (const float*)d_in[1];
    const float* w1   = (const float*)d_in[2];
    const float* w2   = (const float*)d_in[3];
    const float* w3   = (const float*)d_in[4];
    const float* bn0  = (const float*)d_in[5];
    const float* bn1  = (const float*)d_in[6];
    const float* bn2  = (const float*)d_in[7];
    const float* bn3  = (const float*)d_in[8];
    const float* we   = (const float*)d_in[9];
    const float* bne  = (const float*)d_in[10];
    const float* wf0  = (const float*)d_in[11];
    const float* bnf0 = (const float*)d_in[12];
    const float* wf1  = (const float*)d_in[13];
    const float* bnf1 = (const float*)d_in[14];
    const float* wfin = (const float*)d_in[15];
    const float* bfin = (const float*)d_in[16];

    float* ws = (float*)d_ws;
    size_t off = 0;
    float* cat  = ws + off; off += (size_t)BATCH * 512 * N_PTS;        // 16 MB
    float* U    = ws + off; off += (size_t)BATCH * N_PTS * N_PTS;      // 33.5 MB (pd | A+Bv union)
    float* pd   = U;
    float* A    = U;
    float* Bv   = U + (size_t)BATCH * 256 * N_PTS;
    float* xx   = ws + off; off += (size_t)BATCH * N_PTS;
    float* pmax = ws + off; off += (size_t)BATCH * N_PTS * 8;
    float* psum = ws + off; off += (size_t)BATCH * N_PTS * 8;
    float* h0   = ws + off; off += (size_t)BATCH * 2048;
    float* h1   = ws + off; off += (size_t)BATCH * 512;
    float* h2   = ws + off; off += (size_t)BATCH * 256;
    int*   idx  = (int*)(ws + off); off += (size_t)BATCH * N_PTS * KNN;
    ushort_t* weh  = (ushort_t*)(ws + off); off += (size_t)(1024 * 512) / 2;       // 1 MB
    ushort_t* catT = (ushort_t*)(ws + off); off += (size_t)BATCH * N_PTS * 512 / 2; // 8 MB

    const int CSTR = 512 * N_PTS;   // cat batch stride
    const dim3 pdGrid(16, 16, BATCH);
    const int  topkBlocks = BATCH * N_PTS / 4;

    // we -> bf16 (independent, run first)
    wconv_kernel<<<512, 256, 0, stream>>>(we, weh);

    // ---- block 0: input x (B,3,N), out -> cat ch [0,64)
    xx_kernel<<<32, 256, 0, stream>>>(x, xx, 3, 3 * N_PTS);
    pd_kernel<<<pdGrid, 256, 0, stream>>>(x, xx, pd, 3, 3 * N_PTS);
    topk_kernel<<<topkBlocks, 256, 0, stream>>>(pd, idx);
    abv_kernel<<<dim3(64, BATCH), 256, 0, stream>>>(x, w0, A, Bv, 3, 64, 3 * N_PTS);
    gmax_kernel<<<dim3(16, 16, BATCH), 256, 0, stream>>>(A, Bv, idx, bn0, cat, 64, CSTR);

    // ---- block 1
    xx_kernel<<<32, 256, 0, stream>>>(cat, xx, 64, CSTR);
    pd_kernel<<<pdGrid, 256, 0, stream>>>(cat, xx, pd, 64, CSTR);
    topk_kernel<<<topkBlocks, 256, 0, stream>>>(pd, idx);
    abv_kernel<<<dim3(64, BATCH), 256, 0, stream>>>(cat, w1, A, Bv, 64, 64, CSTR);
    gmax_kernel<<<dim3(16, 16, BATCH), 256, 0, stream>>>(A, Bv, idx, bn1, cat + 64 * N_PTS, 64, CSTR);

    // ---- block 2
    xx_kernel<<<32, 256, 0, stream>>>(cat + 64 * N_PTS, xx, 64, CSTR);
    pd_kernel<<<pdGrid, 256, 0, stream>>>(cat + 64 * N_PTS, xx, pd, 64, CSTR);
    topk_kernel<<<topkBlocks, 256, 0, stream>>>(pd, idx);
    abv_kernel<<<dim3(128, BATCH), 256, 0, stream>>>(cat + 64 * N_PTS, w2, A, Bv, 64, 128, CSTR);
    gmax_kernel<<<dim3(16, 32, BATCH), 256, 0, stream>>>(A, Bv, idx, bn2, cat + 128 * N_PTS, 128, CSTR);

    // ---- block 3
    xx_kernel<<<32, 256, 0, stream>>>(cat + 128 * N_PTS, xx, 128, CSTR);
    pd_kernel<<<pdGrid, 256, 0, stream>>>(cat + 128 * N_PTS, xx, pd, 128, CSTR);
    topk_kernel<<<topkBlocks, 256, 0, stream>>>(pd, idx);
    abv_kernel<<<dim3(256, BATCH), 256, 0, stream>>>(cat + 128 * N_PTS, w3, A, Bv, 128, 256, CSTR);
    gmax_kernel<<<dim3(16, 64, BATCH), 256, 0, stream>>>(A, Bv, idx, bn3, cat + 256 * N_PTS, 256, CSTR);

    // ---- cat -> bf16 transposed, then MFMA embedding + pooling
    catT_kernel<<<dim3(16, 8, BATCH), 256, 0, stream>>>(cat, catT);
    gemm6_mfma<<<dim3(8, 8, BATCH), 256, 0, stream>>>(weh, catT, bne, pmax, psum);
    pool_reduce_kernel<<<32, 256, 0, stream>>>(pmax, psum, h0);

    // ---- FC head
    fc_kernel<<<BATCH * 512, 64, 0, stream>>>(h0, wf0, bnf0, nullptr, h1, 2048, 512, 0);
    fc_kernel<<<BATCH * 256, 64, 0, stream>>>(h1, wf1, bnf1, nullptr, h2, 512, 256, 0);
    fc_kernel<<<BATCH * 64, 64, 0, stream>>>(h2, wfin, nullptr, bfin, (float*)d_out, 256, 64, 1);
}

// Round 4
// 606.819 us; speedup vs baseline: 2.0085x; 1.0499x over previous
//
#include <hip/hip_runtime.h>
#include <math.h>

#define N_PTS 1024
#define BATCH 8
#define KNN 20
#define EPSB 1e-5f
#define SLOPE 0.2f

typedef __attribute__((ext_vector_type(8))) short short8;
typedef __attribute__((ext_vector_type(4))) float f32x4;
typedef unsigned short ushort_t;

__device__ __forceinline__ float lrelu(float y) { return y > 0.f ? y : SLOPE * y; }

__device__ __forceinline__ ushort_t f2bf(float f) {
    union { float f; unsigned u; } v; v.f = f;
    unsigned r = v.u + 0x7FFF + ((v.u >> 16) & 1);   // RNE
    return (ushort_t)(r >> 16);
}

// ---------------- squared norms: xx[b,n] = sum_c x[b,c,n]^2 ----------------
__global__ void xx_kernel(const float* __restrict__ x, float* __restrict__ xx,
                          int C, int bstride) {
    int g = blockIdx.x * 256 + threadIdx.x;   // b*N + n
    int b = g >> 10, n = g & 1023;
    const float* xb = x + (size_t)b * bstride;
    float s = 0.f;
    for (int c = 0; c < C; c++) { float v = xb[c * N_PTS + n]; s += v * v; }
    xx[g] = s;
}

// ---------------- pd[b,n,m] = 2*dot(x_n,x_m) - xx[n] - xx[m] ----------------
// 128x128 tile, 256 threads as 16x16, 8x8 microtile (2x2 blocks of 4x4 at +64).
__global__ void __launch_bounds__(256)
pd_kernel(const float* __restrict__ x, const float* __restrict__ xx,
          float* __restrict__ pd, int C, int bstride) {
    int b = blockIdx.z;
    int m0 = blockIdx.x * 128;
    int n0 = blockIdx.y * 128;
    int tid = threadIdx.x;
    int tx = tid & 15, ty = tid >> 4;
    __shared__ float sN[16][128];
    __shared__ float sM[16][128];
    const float* xb = x + (size_t)b * bstride;
    float acc[8][8] = {};
    for (int c0 = 0; c0 < C; c0 += 16) {
        for (int q = 0; q < 2; q++) {
            int f = q * 256 + tid;           // float4 id, 512 per array
            int r = f >> 5, col = (f & 31) * 4;
            int c = c0 + r;
            float4 vn = {0.f, 0.f, 0.f, 0.f}, vm = {0.f, 0.f, 0.f, 0.f};
            if (c < C) {
                vn = *(const float4*)&xb[(size_t)c * N_PTS + n0 + col];
                vm = *(const float4*)&xb[(size_t)c * N_PTS + m0 + col];
            }
            *(float4*)&sN[r][col] = vn;
            *(float4*)&sM[r][col] = vm;
        }
        __syncthreads();
        for (int k = 0; k < 16; k++) {
            float4 a0 = *(const float4*)&sN[k][ty * 4];
            float4 a1 = *(const float4*)&sN[k][64 + ty * 4];
            float4 b0 = *(const float4*)&sM[k][tx * 4];
            float4 b1 = *(const float4*)&sM[k][64 + tx * 4];
            float av[8] = {a0.x, a0.y, a0.z, a0.w, a1.x, a1.y, a1.z, a1.w};
            float bw[8] = {b0.x, b0.y, b0.z, b0.w, b1.x, b1.y, b1.z, b1.w};
            for (int i = 0; i < 8; i++)
                for (int j = 0; j < 8; j++) acc[i][j] += av[i] * bw[j];
        }
        __syncthreads();
    }
    float xnv[8], xmv[8];
    for (int i = 0; i < 8; i++) xnv[i] = xx[b * N_PTS + n0 + (i >> 2) * 64 + ty * 4 + (i & 3)];
    for (int j = 0; j < 8; j++) xmv[j] = xx[b * N_PTS + m0 + (j >> 2) * 64 + tx * 4 + (j & 3)];
    for (int i = 0; i < 8; i++) {
        int n = n0 + (i >> 2) * 64 + ty * 4 + (i & 3);
        float* prow = pd + ((size_t)(b * N_PTS + n)) * N_PTS;
        for (int jh = 0; jh < 2; jh++) {
            float4 o;
            o.x = 2.f * acc[i][jh * 4 + 0] - xnv[i] - xmv[jh * 4 + 0];
            o.y = 2.f * acc[i][jh * 4 + 1] - xnv[i] - xmv[jh * 4 + 1];
            o.z = 2.f * acc[i][jh * 4 + 2] - xnv[i] - xmv[jh * 4 + 2];
            o.w = 2.f * acc[i][jh * 4 + 3] - xnv[i] - xmv[jh * 4 + 3];
            *(float4*)&prow[m0 + jh * 64 + tx * 4] = o;
        }
    }
}

// ---------------- top-20 per row, one wave per row, barrier-free ----------------
__global__ void topk_kernel(const float* __restrict__ pd, int* __restrict__ idx) {
    int row = blockIdx.x * 4 + (threadIdx.x >> 6);   // row = b*N + n
    int lane = threadIdx.x & 63;
    const float* p = pd + (size_t)row * N_PTS;
    float v[16];
    for (int q = 0; q < 4; q++) {
        float4 t = *(const float4*)&p[lane * 16 + q * 4];
        v[q * 4 + 0] = t.x; v[q * 4 + 1] = t.y; v[q * 4 + 2] = t.z; v[q * 4 + 3] = t.w;
    }
    for (int kk = 0; kk < KNN; kk++) {
        float bv = v[0]; int bj = 0;
        for (int j = 1; j < 16; j++) if (v[j] > bv) { bv = v[j]; bj = j; }
        int bi = lane * 16 + bj;
        for (int s = 32; s > 0; s >>= 1) {
            float ov = __shfl_down(bv, s, 64);
            int oi = __shfl_down(bi, s, 64);
            if (ov > bv || (ov == bv && oi < bi)) { bv = ov; bi = oi; }
        }
        bi = __shfl(bi, 0, 64);
        if ((bi >> 4) == lane) v[bi & 15] = -INFINITY;
        if (lane == 0) idx[row * KNN + kk] = bi;
    }
}

// ---------------- W' prep: wpt[c][m] (k-major), m<Cout: wl, else wd ----------------
__global__ void wprep_kernel(const float* __restrict__ w, float* __restrict__ wpt,
                             int C, int Cout) {
    int g = blockIdx.x * 256 + threadIdx.x;
    int M2 = 2 * Cout;
    if (g >= C * M2) return;
    int c = g / M2, m = g - c * M2;
    float v;
    if (m < Cout) v = w[(size_t)m * 2 * C + c];
    else {
        int o = m - Cout;
        v = w[(size_t)o * 2 * C + C + c] - w[(size_t)o * 2 * C + c];
    }
    wpt[(size_t)c * M2 + m] = v;
}

// ---------------- [A;Bv] = W' * x : M=2*Cout, K=C, N per batch ----------------
// 128x128 tile, 8x8 microtile, same structure as pd_kernel.
__global__ void __launch_bounds__(256)
abv_gemm(const float* __restrict__ x, const float* __restrict__ wpt,
         float* __restrict__ A, float* __restrict__ Bv,
         int C, int Cout, int bstride) {
    int b = blockIdx.z;
    int m0 = blockIdx.y * 128;   // row tile in M2 = 2*Cout
    int n0 = blockIdx.x * 128;
    int M2 = 2 * Cout;
    int tid = threadIdx.x;
    int tx = tid & 15, ty = tid >> 4;
    __shared__ float sW[16][128];   // [k][m-local]
    __shared__ float sX[16][128];   // [k][n-local]
    const float* xb = x + (size_t)b * bstride;
    float acc[8][8] = {};
    for (int c0 = 0; c0 < C; c0 += 16) {
        for (int q = 0; q < 2; q++) {
            int f = q * 256 + tid;
            int r = f >> 5, col = (f & 31) * 4;
            int c = c0 + r;
            float4 vw = {0.f, 0.f, 0.f, 0.f}, vx = {0.f, 0.f, 0.f, 0.f};
            if (c < C) {
                vw = *(const float4*)&wpt[(size_t)c * M2 + m0 + col];
                vx = *(const float4*)&xb[(size_t)c * N_PTS + n0 + col];
            }
            *(float4*)&sW[r][col] = vw;
            *(float4*)&sX[r][col] = vx;
        }
        __syncthreads();
        for (int k = 0; k < 16; k++) {
            float4 a0 = *(const float4*)&sW[k][ty * 4];
            float4 a1 = *(const float4*)&sW[k][64 + ty * 4];
            float4 b0 = *(const float4*)&sX[k][tx * 4];
            float4 b1 = *(const float4*)&sX[k][64 + tx * 4];
            float av[8] = {a0.x, a0.y, a0.z, a0.w, a1.x, a1.y, a1.z, a1.w};
            float bw[8] = {b0.x, b0.y, b0.z, b0.w, b1.x, b1.y, b1.z, b1.w};
            for (int i = 0; i < 8; i++)
                for (int j = 0; j < 8; j++) acc[i][j] += av[i] * bw[j];
        }
        __syncthreads();
    }
    for (int i = 0; i < 8; i++) {
        int row = m0 + (i >> 2) * 64 + ty * 4 + (i & 3);
        float* dst = (row < Cout) ? (A + ((size_t)b * Cout + row) * N_PTS)
                                  : (Bv + ((size_t)b * Cout + row - Cout) * N_PTS);
        for (int jh = 0; jh < 2; jh++) {
            float4 o;
            o.x = acc[i][jh * 4 + 0];
            o.y = acc[i][jh * 4 + 1];
            o.z = acc[i][jh * 4 + 2];
            o.w = acc[i][jh * 4 + 3];
            *(float4*)&dst[n0 + jh * 64 + tx * 4] = o;
        }
    }
}

// ---------------- out[b,o,n] = lrelu(bn(max_k A[b,o,idx[n,k]] + Bv[b,o,n])) ----------------
__global__ void gmax_kernel(const float* __restrict__ A, const float* __restrict__ Bv,
                            const int* __restrict__ idx, const float* __restrict__ bnp,
                            float* __restrict__ out, int Cout, int outStrideB) {
    int b = blockIdx.z;
    int n0 = blockIdx.x * 64;
    int o0 = blockIdx.y * 4;
    int tid = threadIdx.x;
    int nl = tid & 63, ol = tid >> 6;
    __shared__ int sidx[64 * KNN];
    for (int t = tid; t < 64 * KNN; t += 256) sidx[t] = idx[(b * N_PTS + n0) * KNN + t];
    __syncthreads();
    int o = o0 + ol;
    const float* Ao = A + ((size_t)b * Cout + o) * N_PTS;
    float best = -INFINITY;
    for (int k = 0; k < KNN; k++) {
        int j = sidx[nl * KNN + k];
        best = fmaxf(best, Ao[j]);
    }
    int n = n0 + nl;
    float pre = best + Bv[((size_t)b * Cout + o) * N_PTS + n];
    float g = bnp[o], bb = bnp[Cout + o], m = bnp[2 * Cout + o], vv = bnp[3 * Cout + o];
    float scale = g / sqrtf(vv + EPSB);
    out[(size_t)b * outStrideB + (size_t)o * N_PTS + n] = lrelu((pre - m) * scale + bb);
}

// ---------------- we fp32 -> bf16 ----------------
__global__ void wconv_kernel(const float* __restrict__ w, ushort_t* __restrict__ wh) {
    int g = blockIdx.x * 256 + threadIdx.x;       // element-group of 4
    float4 v = ((const float4*)w)[g];
    ushort4 o;
    o.x = f2bf(v.x); o.y = f2bf(v.y); o.z = f2bf(v.z); o.w = f2bf(v.w);
    ((ushort4*)wh)[g] = o;
}

// ---------------- cat fp32 [b][c][n] -> catT bf16 [b][n][c] ----------------
__global__ void catT_kernel(const float* __restrict__ cat, ushort_t* __restrict__ catT) {
    int b = blockIdx.z, ct = blockIdx.y, nt = blockIdx.x;
    int tid = threadIdx.x;
    __shared__ float tile[64][65];
    const float* cb = cat + (size_t)b * 512 * N_PTS;
    for (int q = 0; q < 16; q++) {
        int e = q * 256 + tid;
        int c = e >> 6, n = e & 63;
        tile[c][n] = cb[(size_t)(ct * 64 + c) * N_PTS + nt * 64 + n];
    }
    __syncthreads();
    for (int q = 0; q < 16; q++) {
        int e = q * 256 + tid;
        int n = e >> 6, c = e & 63;
        catT[((size_t)b * N_PTS + nt * 64 + n) * 512 + ct * 64 + c] = f2bf(tile[c][n]);
    }
}

// ---------------- embedding GEMM (bf16 MFMA) + bn + lrelu + fused max/sum ----------------
__global__ void __launch_bounds__(256)
gemm6_mfma(const ushort_t* __restrict__ weh, const ushort_t* __restrict__ catT,
           const float* __restrict__ bne,
           float* __restrict__ pmax, float* __restrict__ psum) {
    int b = blockIdx.z, ot = blockIdx.y, nt = blockIdx.x;
    int tid = threadIdx.x;
    int w = tid >> 6, lane = tid & 63, q = lane >> 4, lr = lane & 15;
    int mblk = w >> 1, nblk = w & 1;
    __shared__ __align__(16) ushort_t sA[128 * 40];
    __shared__ __align__(16) ushort_t sB[128 * 40];
    __shared__ float sa[128], sc[128];
    __shared__ float redmax[128][2], redsum[128][2];
    int o0 = ot * 128, n0 = nt * 128;
    if (tid < 128) {
        int o = o0 + tid;
        float g = bne[o], bb = bne[1024 + o], m = bne[2048 + o], vv = bne[3072 + o];
        float scale = g / sqrtf(vv + EPSB);
        sa[tid] = scale; sc[tid] = bb - m * scale;
    }
    f32x4 acc[4][4] = {};
    const ushort_t* cT = catT + (size_t)b * N_PTS * 512;
    int r0 = tid >> 2, s = tid & 3;
    for (int k0 = 0; k0 < 512; k0 += 32) {
        __syncthreads();
        for (int h = 0; h < 2; h++) {
            int r = r0 + h * 64;
            *(short8*)&sA[r * 40 + s * 8] = *(const short8*)(weh + (size_t)(o0 + r) * 512 + k0 + s * 8);
            *(short8*)&sB[r * 40 + s * 8] = *(const short8*)(cT  + (size_t)(n0 + r) * 512 + k0 + s * 8);
        }
        __syncthreads();
        short8 af[4], bfr[4];
        for (int mi = 0; mi < 4; mi++)
            af[mi] = *(const short8*)&sA[(mblk * 64 + mi * 16 + lr) * 40 + q * 8];
        for (int ni = 0; ni < 4; ni++)
            bfr[ni] = *(const short8*)&sB[(nblk * 64 + ni * 16 + lr) * 40 + q * 8];
        for (int mi = 0; mi < 4; mi++)
            for (int ni = 0; ni < 4; ni++)
                acc[mi][ni] = __builtin_amdgcn_mfma_f32_16x16x32_bf16(af[mi], bfr[ni], acc[mi][ni], 0, 0, 0);
    }
    for (int mi = 0; mi < 4; mi++) {
        for (int r = 0; r < 4; r++) {
            int row = mblk * 64 + mi * 16 + q * 4 + r;
            float a = sa[row], c = sc[row];
            float mx = -INFINITY, sm = 0.f;
            for (int ni = 0; ni < 4; ni++) {
                float y = lrelu(acc[mi][ni][r] * a + c);
                mx = fmaxf(mx, y); sm += y;
            }
            for (int msk = 1; msk < 16; msk <<= 1) {
                mx = fmaxf(mx, __shfl_xor(mx, msk, 16));
                sm += __shfl_xor(sm, msk, 16);
            }
            if (lr == 0) { redmax[row][nblk] = mx; redsum[row][nblk] = sm; }
        }
    }
    __syncthreads();
    if (tid < 128) {
        float mx = fmaxf(redmax[tid][0], redmax[tid][1]);
        float sm = redsum[tid][0] + redsum[tid][1];
        int o = o0 + tid;
        pmax[((size_t)(b * 1024 + o)) * 8 + nt] = mx;
        psum[((size_t)(b * 1024 + o)) * 8 + nt] = sm;
    }
}

__global__ void pool_reduce_kernel(const float* __restrict__ pmax, const float* __restrict__ psum,
                                   float* __restrict__ h0) {
    int g = blockIdx.x * 256 + threadIdx.x;  // b*1024 + o
    int b = g >> 10, o = g & 1023;
    float mx = -INFINITY, sm = 0.f;
    for (int t = 0; t < 8; t++) { mx = fmaxf(mx, pmax[g * 8 + t]); sm += psum[g * 8 + t]; }
    h0[(size_t)b * 2048 + o] = mx;
    h0[(size_t)b * 2048 + 1024 + o] = sm * (1.0f / 1024.0f);
}

// ---------------- FC: one wave per output ----------------
__global__ void fc_kernel(const float* __restrict__ in, const float* __restrict__ w,
                          const float* __restrict__ bnp, const float* __restrict__ bias,
                          float* __restrict__ out, int Cin, int Cout, int mode) {
    int blk = blockIdx.x;  // b*Cout + o
    int b = blk / Cout, o = blk % Cout;
    int lane = threadIdx.x;
    const float* inb = in + (size_t)b * Cin;
    const float* wo = w + (size_t)o * Cin;
    float acc = 0.f;
    for (int c = lane; c < Cin; c += 64) acc += inb[c] * wo[c];
    for (int s = 32; s > 0; s >>= 1) acc += __shfl_down(acc, s, 64);
    if (lane == 0) {
        float y = acc;
        if (mode == 0) {
            float g = bnp[o], bb = bnp[Cout + o], m = bnp[2 * Cout + o], vv = bnp[3 * Cout + o];
            y = lrelu((y - m) * (g / sqrtf(vv + EPSB)) + bb);
        } else {
            y += bias[o];
        }
        out[(size_t)b * Cout + o] = y;
    }
}

extern "C" void kernel_launch(void* const* d_in, const int* in_sizes, int n_in,
                              void* d_out, int out_size, void* d_ws, size_t ws_size,
                              hipStream_t stream) {
    const float* x    = (const float*)d_in[0];
    const float* w0   = (const float*)d_in[1];
    const float* w1   = (const float*)d_in[2];
    const float* w2   = (const float*)d_in[3];
    const float* w3   = (const float*)d_in[4];
    const float* bn0  = (const float*)d_in[5];
    const float* bn1  = (const float*)d_in[6];
    const float* bn2  = (const float*)d_in[7];
    const float* bn3  = (const float*)d_in[8];
    const float* we   = (const float*)d_in[9];
    const float* bne  = (const float*)d_in[10];
    const float* wf0  = (const float*)d_in[11];
    const float* bnf0 = (const float*)d_in[12];
    const float* wf1  = (const float*)d_in[13];
    const float* bnf1 = (const float*)d_in[14];
    const float* wfin = (const float*)d_in[15];
    const float* bfin = (const float*)d_in[16];

    float* ws = (float*)d_ws;
    size_t off = 0;
    float* cat  = ws + off; off += (size_t)BATCH * 512 * N_PTS;        // 16 MB
    float* U    = ws + off; off += (size_t)BATCH * N_PTS * N_PTS;      // 33.5 MB (pd | A+Bv union)
    float* pd   = U;
    float* A    = U;
    float* Bv   = U + (size_t)BATCH * 256 * N_PTS;
    float* xx   = ws + off; off += (size_t)BATCH * N_PTS;
    float* pmax = ws + off; off += (size_t)BATCH * N_PTS * 8;
    float* psum = ws + off; off += (size_t)BATCH * N_PTS * 8;
    float* h0   = ws + off; off += (size_t)BATCH * 2048;
    float* h1   = ws + off; off += (size_t)BATCH * 512;
    float* h2   = ws + off; off += (size_t)BATCH * 256;
    int*   idx  = (int*)(ws + off); off += (size_t)BATCH * N_PTS * KNN;
    ushort_t* weh  = (ushort_t*)(ws + off); off += (size_t)(1024 * 512) / 2;        // 1 MB
    ushort_t* catT = (ushort_t*)(ws + off); off += (size_t)BATCH * N_PTS * 512 / 2; // 8 MB
    float* wpt  = ws + off; off += (size_t)128 * 512;                   // 256 KB W' buffer

    const int CSTR = 512 * N_PTS;   // cat batch stride
    const dim3 pdGrid(8, 8, BATCH);
    const int  topkBlocks = BATCH * N_PTS / 4;

    // we -> bf16 (independent, run first)
    wconv_kernel<<<512, 256, 0, stream>>>(we, weh);

    // ---- block 0: input x (B,3,N), C=3 -> Cout=64, out ch [0,64)
    xx_kernel<<<32, 256, 0, stream>>>(x, xx, 3, 3 * N_PTS);
    pd_kernel<<<pdGrid, 256, 0, stream>>>(x, xx, pd, 3, 3 * N_PTS);
    topk_kernel<<<topkBlocks, 256, 0, stream>>>(pd, idx);
    wprep_kernel<<<(3 * 128 + 255) / 256, 256, 0, stream>>>(w0, wpt, 3, 64);
    abv_gemm<<<dim3(8, 1, BATCH), 256, 0, stream>>>(x, wpt, A, Bv, 3, 64, 3 * N_PTS);
    gmax_kernel<<<dim3(16, 16, BATCH), 256, 0, stream>>>(A, Bv, idx, bn0, cat, 64, CSTR);

    // ---- block 1: C=64 -> Cout=64, out ch [64,128)
    xx_kernel<<<32, 256, 0, stream>>>(cat, xx, 64, CSTR);
    pd_kernel<<<pdGrid, 256, 0, stream>>>(cat, xx, pd, 64, CSTR);
    topk_kernel<<<topkBlocks, 256, 0, stream>>>(pd, idx);
    wprep_kernel<<<(64 * 128 + 255) / 256, 256, 0, stream>>>(w1, wpt, 64, 64);
    abv_gemm<<<dim3(8, 1, BATCH), 256, 0, stream>>>(cat, wpt, A, Bv, 64, 64, CSTR);
    gmax_kernel<<<dim3(16, 16, BATCH), 256, 0, stream>>>(A, Bv, idx, bn1, cat + 64 * N_PTS, 64, CSTR);

    // ---- block 2: C=64 -> Cout=128, out ch [128,256)
    xx_kernel<<<32, 256, 0, stream>>>(cat + 64 * N_PTS, xx, 64, CSTR);
    pd_kernel<<<pdGrid, 256, 0, stream>>>(cat + 64 * N_PTS, xx, pd, 64, CSTR);
    topk_kernel<<<topkBlocks, 256, 0, stream>>>(pd, idx);
    wprep_kernel<<<(64 * 256 + 255) / 256, 256, 0, stream>>>(w2, wpt, 64, 128);
    abv_gemm<<<dim3(8, 2, BATCH), 256, 0, stream>>>(cat + 64 * N_PTS, wpt, A, Bv, 64, 128, CSTR);
    gmax_kernel<<<dim3(16, 32, BATCH), 256, 0, stream>>>(A, Bv, idx, bn2, cat + 128 * N_PTS, 128, CSTR);

    // ---- block 3: C=128 -> Cout=256, out ch [256,512)
    xx_kernel<<<32, 256, 0, stream>>>(cat + 128 * N_PTS, xx, 128, CSTR);
    pd_kernel<<<pdGrid, 256, 0, stream>>>(cat + 128 * N_PTS, xx, pd, 128, CSTR);
    topk_kernel<<<topkBlocks, 256, 0, stream>>>(pd, idx);
    wprep_kernel<<<(128 * 512 + 255) / 256, 256, 0, stream>>>(w3, wpt, 128, 256);
    abv_gemm<<<dim3(8, 4, BATCH), 256, 0, stream>>>(cat + 128 * N_PTS, wpt, A, Bv, 128, 256, CSTR);
    gmax_kernel<<<dim3(16, 64, BATCH), 256, 0, stream>>>(A, Bv, idx, bn3, cat + 256 * N_PTS, 256, CSTR);

    // ---- cat -> bf16 transposed, then MFMA embedding + pooling
    catT_kernel<<<dim3(16, 8, BATCH), 256, 0, stream>>>(cat, catT);
    gemm6_mfma<<<dim3(8, 8, BATCH), 256, 0, stream>>>(weh, catT, bne, pmax, psum);
    pool_reduce_kernel<<<32, 256, 0, stream>>>(pmax, psum, h0);

    // ---- FC head
    fc_kernel<<<BATCH * 512, 64, 0, stream>>>(h0, wf0, bnf0, nullptr, h1, 2048, 512, 0);
    fc_kernel<<<BATCH * 256, 64, 0, stream>>>(h1, wf1, bnf1, nullptr, h2, 512, 256, 0);
    fc_kernel<<<BATCH * 64, 64, 0, stream>>>(h2, wfin, nullptr, bfin, (float*)d_out, 256, 64, 1);
}

// Round 5
// 485.884 us; speedup vs baseline: 2.5084x; 1.2489x over previous
//
#include <hip/hip_runtime.h>
#include <math.h>

#define N_PTS 1024
#define BATCH 8
#define KNN 20
#define EPSB 1e-5f
#define SLOPE 0.2f

typedef __attribute__((ext_vector_type(8))) short short8;
typedef __attribute__((ext_vector_type(4))) float f32x4;
typedef unsigned short ushort_t;
typedef unsigned long long u64;

__device__ __forceinline__ float lrelu(float y) { return y > 0.f ? y : SLOPE * y; }

__device__ __forceinline__ ushort_t f2bf(float f) {
    union { float f; unsigned u; } v; v.f = f;
    unsigned r = v.u + 0x7FFF + ((v.u >> 16) & 1);   // RNE
    return (ushort_t)(r >> 16);
}

// ---------------- squared norms: xx[b,n] = sum_c x[b,c,n]^2 ----------------
__global__ void xx_kernel(const float* __restrict__ x, float* __restrict__ xx,
                          int C, int bstride) {
    int g = blockIdx.x * 256 + threadIdx.x;   // b*N + n
    int b = g >> 10, n = g & 1023;
    const float* xb = x + (size_t)b * bstride;
    float s = 0.f;
    for (int c = 0; c < C; c++) { float v = xb[c * N_PTS + n]; s += v * v; }
    xx[g] = s;
}

// ---------------- pd[b,n,m] = 2*dot(x_n,x_m) - xx[n] - xx[m] ----------------
// 128x128 tile, 256 threads as 16x16, 8x8 microtile (2x2 blocks of 4x4 at +64).
__global__ void __launch_bounds__(256)
pd_kernel(const float* __restrict__ x, const float* __restrict__ xx,
          float* __restrict__ pd, int C, int bstride) {
    int b = blockIdx.z;
    int m0 = blockIdx.x * 128;
    int n0 = blockIdx.y * 128;
    int tid = threadIdx.x;
    int tx = tid & 15, ty = tid >> 4;
    __shared__ float sN[16][128];
    __shared__ float sM[16][128];
    const float* xb = x + (size_t)b * bstride;
    float acc[8][8] = {};
    for (int c0 = 0; c0 < C; c0 += 16) {
        for (int q = 0; q < 2; q++) {
            int f = q * 256 + tid;           // float4 id, 512 per array
            int r = f >> 5, col = (f & 31) * 4;
            int c = c0 + r;
            float4 vn = {0.f, 0.f, 0.f, 0.f}, vm = {0.f, 0.f, 0.f, 0.f};
            if (c < C) {
                vn = *(const float4*)&xb[(size_t)c * N_PTS + n0 + col];
                vm = *(const float4*)&xb[(size_t)c * N_PTS + m0 + col];
            }
            *(float4*)&sN[r][col] = vn;
            *(float4*)&sM[r][col] = vm;
        }
        __syncthreads();
        for (int k = 0; k < 16; k++) {
            float4 a0 = *(const float4*)&sN[k][ty * 4];
            float4 a1 = *(const float4*)&sN[k][64 + ty * 4];
            float4 b0 = *(const float4*)&sM[k][tx * 4];
            float4 b1 = *(const float4*)&sM[k][64 + tx * 4];
            float av[8] = {a0.x, a0.y, a0.z, a0.w, a1.x, a1.y, a1.z, a1.w};
            float bw[8] = {b0.x, b0.y, b0.z, b0.w, b1.x, b1.y, b1.z, b1.w};
            for (int i = 0; i < 8; i++)
                for (int j = 0; j < 8; j++) acc[i][j] += av[i] * bw[j];
        }
        __syncthreads();
    }
    float xnv[8], xmv[8];
    for (int i = 0; i < 8; i++) xnv[i] = xx[b * N_PTS + n0 + (i >> 2) * 64 + ty * 4 + (i & 3)];
    for (int j = 0; j < 8; j++) xmv[j] = xx[b * N_PTS + m0 + (j >> 2) * 64 + tx * 4 + (j & 3)];
    for (int i = 0; i < 8; i++) {
        int n = n0 + (i >> 2) * 64 + ty * 4 + (i & 3);
        float* prow = pd + ((size_t)(b * N_PTS + n)) * N_PTS;
        for (int jh = 0; jh < 2; jh++) {
            float4 o;
            o.x = 2.f * acc[i][jh * 4 + 0] - xnv[i] - xmv[jh * 4 + 0];
            o.y = 2.f * acc[i][jh * 4 + 1] - xnv[i] - xmv[jh * 4 + 1];
            o.z = 2.f * acc[i][jh * 4 + 2] - xnv[i] - xmv[jh * 4 + 2];
            o.w = 2.f * acc[i][jh * 4 + 3] - xnv[i] - xmv[jh * 4 + 3];
            *(float4*)&prow[m0 + jh * 64 + tx * 4] = o;
        }
    }
}

// ---------------- top-20 per row: threshold-compact + bitonic select ----------------
// One wave per row. t' = 20th-largest of per-lane maxima (provably <= 20th-largest
// overall), compact {v >= t'} (E[count] ~ 24) into LDS as packed u64 keys, one
// 64-lane u64 bitonic sort emits the exact top-20 (ties -> lower index, = lax.top_k).
// Wave-uniform fallback to the full iterative scan if survivors > 64 (prob ~ 0).
__global__ void __launch_bounds__(256)
topk_kernel(const float* __restrict__ pd, int* __restrict__ idx) {
    int wid = threadIdx.x >> 6;
    int row = blockIdx.x * 4 + wid;          // row = b*N + n
    int lane = threadIdx.x & 63;
    __shared__ u64 Sk[4][64];
    const float* p = pd + (size_t)row * N_PTS;
    float v[16];
    for (int q = 0; q < 4; q++) {
        float4 t = *(const float4*)&p[lane * 16 + q * 4];
        v[q * 4 + 0] = t.x; v[q * 4 + 1] = t.y; v[q * 4 + 2] = t.z; v[q * 4 + 3] = t.w;
    }
    // per-lane max
    float lmax = v[0];
    #pragma unroll
    for (int j = 1; j < 16; j++) lmax = fmaxf(lmax, v[j]);
    // bitonic sort (ascending) of lane maxima across the wave
    float s = lmax;
    #pragma unroll
    for (int k = 2; k <= 64; k <<= 1) {
        #pragma unroll
        for (int j = k >> 1; j > 0; j >>= 1) {
            float o = __shfl_xor(s, j, 64);
            bool takeMin = (((lane & k) == 0) == ((lane & j) == 0));
            float mn = fminf(s, o), mx = fmaxf(s, o);
            s = takeMin ? mn : mx;
        }
    }
    float tp = __shfl(s, 44, 64);            // 20th largest lane-max
    // hitmask + wave prefix scan for compact slots (slot order = m ascending)
    unsigned hm = 0;
    #pragma unroll
    for (int j = 0; j < 16; j++) hm |= (v[j] >= tp ? 1u : 0u) << j;
    int cnt = __popc(hm);
    int incl = cnt;
    #pragma unroll
    for (int d = 1; d < 64; d <<= 1) {
        int o = __shfl_up(incl, d, 64);
        if (lane >= d) incl += o;
    }
    int total = __shfl(incl, 63, 64);
    int pos = incl - cnt;
    if (total <= 64) {
        #pragma unroll
        for (int j = 0; j < 16; j++) {
            if (hm & (1u << j)) {
                unsigned u = __float_as_uint(v[j]);
                unsigned msk = ((unsigned)((int)u >> 31)) | 0x80000000u;
                Sk[wid][pos] = ((u64)(u ^ msk) << 32) | (unsigned)(1023 - (lane * 16 + j));
                pos++;
            }
        }
        u64 key = (lane < total) ? Sk[wid][lane] : 0ull;
        // bitonic sort ascending on u64 keys (value-major, lower m wins ties)
        #pragma unroll
        for (int k = 2; k <= 64; k <<= 1) {
            #pragma unroll
            for (int j = k >> 1; j > 0; j >>= 1) {
                u64 o = __shfl_xor(key, j, 64);
                bool takeMin = (((lane & k) == 0) == ((lane & j) == 0));
                bool sgt = key > o;
                key = (sgt != takeMin) ? key : o;
            }
        }
        if (lane >= 44) {
            int m = 1023 - (int)(unsigned)(key & 0xFFFFFFFFu);
            idx[row * KNN + (63 - lane)] = m;
        }
    } else {
        // rare exact fallback: iterative argmax (R4 algorithm)
        for (int kk = 0; kk < KNN; kk++) {
            float bv = v[0]; int bj = 0;
            #pragma unroll
            for (int j = 1; j < 16; j++) if (v[j] > bv) { bv = v[j]; bj = j; }
            int bi = lane * 16 + bj;
            for (int d = 32; d > 0; d >>= 1) {
                float ov = __shfl_down(bv, d, 64);
                int oi = __shfl_down(bi, d, 64);
                if (ov > bv || (ov == bv && oi < bi)) { bv = ov; bi = oi; }
            }
            bi = __shfl(bi, 0, 64);
            if ((bi >> 4) == lane) {
                #pragma unroll
                for (int j = 0; j < 16; j++) if (j == (bi & 15)) v[j] = -INFINITY;
            }
            if (lane == 0) idx[row * KNN + kk] = bi;
        }
    }
}

// ---------------- W' prep: wpt[c][m] (k-major), m<Cout: wl, else wd ----------------
__global__ void wprep_kernel(const float* __restrict__ w, float* __restrict__ wpt,
                             int C, int Cout) {
    int g = blockIdx.x * 256 + threadIdx.x;
    int M2 = 2 * Cout;
    if (g >= C * M2) return;
    int c = g / M2, m = g - c * M2;
    float v;
    if (m < Cout) v = w[(size_t)m * 2 * C + c];
    else {
        int o = m - Cout;
        v = w[(size_t)o * 2 * C + C + c] - w[(size_t)o * 2 * C + c];
    }
    wpt[(size_t)c * M2 + m] = v;
}

// ---------------- [A;Bv] = W' * x : M=2*Cout, K=C, N per batch ----------------
__global__ void __launch_bounds__(256)
abv_gemm(const float* __restrict__ x, const float* __restrict__ wpt,
         float* __restrict__ A, float* __restrict__ Bv,
         int C, int Cout, int bstride) {
    int b = blockIdx.z;
    int m0 = blockIdx.y * 128;   // row tile in M2 = 2*Cout
    int n0 = blockIdx.x * 128;
    int M2 = 2 * Cout;
    int tid = threadIdx.x;
    int tx = tid & 15, ty = tid >> 4;
    __shared__ float sW[16][128];   // [k][m-local]
    __shared__ float sX[16][128];   // [k][n-local]
    const float* xb = x + (size_t)b * bstride;
    float acc[8][8] = {};
    for (int c0 = 0; c0 < C; c0 += 16) {
        for (int q = 0; q < 2; q++) {
            int f = q * 256 + tid;
            int r = f >> 5, col = (f & 31) * 4;
            int c = c0 + r;
            float4 vw = {0.f, 0.f, 0.f, 0.f}, vx = {0.f, 0.f, 0.f, 0.f};
            if (c < C) {
                vw = *(const float4*)&wpt[(size_t)c * M2 + m0 + col];
                vx = *(const float4*)&xb[(size_t)c * N_PTS + n0 + col];
            }
            *(float4*)&sW[r][col] = vw;
            *(float4*)&sX[r][col] = vx;
        }
        __syncthreads();
        for (int k = 0; k < 16; k++) {
            float4 a0 = *(const float4*)&sW[k][ty * 4];
            float4 a1 = *(const float4*)&sW[k][64 + ty * 4];
            float4 b0 = *(const float4*)&sX[k][tx * 4];
            float4 b1 = *(const float4*)&sX[k][64 + tx * 4];
            float av[8] = {a0.x, a0.y, a0.z, a0.w, a1.x, a1.y, a1.z, a1.w};
            float bw[8] = {b0.x, b0.y, b0.z, b0.w, b1.x, b1.y, b1.z, b1.w};
            for (int i = 0; i < 8; i++)
                for (int j = 0; j < 8; j++) acc[i][j] += av[i] * bw[j];
        }
        __syncthreads();
    }
    for (int i = 0; i < 8; i++) {
        int rowm = m0 + (i >> 2) * 64 + ty * 4 + (i & 3);
        float* dst = (rowm < Cout) ? (A + ((size_t)b * Cout + rowm) * N_PTS)
                                   : (Bv + ((size_t)b * Cout + rowm - Cout) * N_PTS);
        for (int jh = 0; jh < 2; jh++) {
            float4 o;
            o.x = acc[i][jh * 4 + 0];
            o.y = acc[i][jh * 4 + 1];
            o.z = acc[i][jh * 4 + 2];
            o.w = acc[i][jh * 4 + 3];
            *(float4*)&dst[n0 + jh * 64 + tx * 4] = o;
        }
    }
}

// ---------------- out[b,o,n] = lrelu(bn(max_k A[b,o,idx[n,k]] + Bv[b,o,n])) ----------------
__global__ void gmax_kernel(const float* __restrict__ A, const float* __restrict__ Bv,
                            const int* __restrict__ idx, const float* __restrict__ bnp,
                            float* __restrict__ out, int Cout, int outStrideB) {
    int b = blockIdx.z;
    int n0 = blockIdx.x * 64;
    int o0 = blockIdx.y * 4;
    int tid = threadIdx.x;
    int nl = tid & 63, ol = tid >> 6;
    __shared__ int sidx[64 * KNN];
    for (int t = tid; t < 64 * KNN; t += 256) sidx[t] = idx[(b * N_PTS + n0) * KNN + t];
    __syncthreads();
    int o = o0 + ol;
    const float* Ao = A + ((size_t)b * Cout + o) * N_PTS;
    float best = -INFINITY;
    for (int k = 0; k < KNN; k++) {
        int j = sidx[nl * KNN + k];
        best = fmaxf(best, Ao[j]);
    }
    int n = n0 + nl;
    float pre = best + Bv[((size_t)b * Cout + o) * N_PTS + n];
    float g = bnp[o], bb = bnp[Cout + o], m = bnp[2 * Cout + o], vv = bnp[3 * Cout + o];
    float scale = g / sqrtf(vv + EPSB);
    out[(size_t)b * outStrideB + (size_t)o * N_PTS + n] = lrelu((pre - m) * scale + bb);
}

// ---------------- we fp32 -> bf16 ----------------
__global__ void wconv_kernel(const float* __restrict__ w, ushort_t* __restrict__ wh) {
    int g = blockIdx.x * 256 + threadIdx.x;       // element-group of 4
    float4 v = ((const float4*)w)[g];
    ushort4 o;
    o.x = f2bf(v.x); o.y = f2bf(v.y); o.z = f2bf(v.z); o.w = f2bf(v.w);
    ((ushort4*)wh)[g] = o;
}

// ---------------- cat fp32 [b][c][n] -> catT bf16 [b][n][c] ----------------
__global__ void catT_kernel(const float* __restrict__ cat, ushort_t* __restrict__ catT) {
    int b = blockIdx.z, ct = blockIdx.y, nt = blockIdx.x;
    int tid = threadIdx.x;
    __shared__ float tile[64][65];
    const float* cb = cat + (size_t)b * 512 * N_PTS;
    for (int q = 0; q < 16; q++) {
        int e = q * 256 + tid;
        int c = e >> 6, n = e & 63;
        tile[c][n] = cb[(size_t)(ct * 64 + c) * N_PTS + nt * 64 + n];
    }
    __syncthreads();
    for (int q = 0; q < 16; q++) {
        int e = q * 256 + tid;
        int n = e >> 6, c = e & 63;
        catT[((size_t)b * N_PTS + nt * 64 + n) * 512 + ct * 64 + c] = f2bf(tile[c][n]);
    }
}

// ---------------- embedding GEMM (bf16 MFMA) + bn + lrelu + fused max/sum ----------------
__global__ void __launch_bounds__(256)
gemm6_mfma(const ushort_t* __restrict__ weh, const ushort_t* __restrict__ catT,
           const float* __restrict__ bne,
           float* __restrict__ pmax, float* __restrict__ psum) {
    int b = blockIdx.z, ot = blockIdx.y, nt = blockIdx.x;
    int tid = threadIdx.x;
    int w = tid >> 6, lane = tid & 63, q = lane >> 4, lr = lane & 15;
    int mblk = w >> 1, nblk = w & 1;
    __shared__ __align__(16) ushort_t sA[128 * 40];
    __shared__ __align__(16) ushort_t sB[128 * 40];
    __shared__ float sa[128], sc[128];
    __shared__ float redmax[128][2], redsum[128][2];
    int o0 = ot * 128, n0 = nt * 128;
    if (tid < 128) {
        int o = o0 + tid;
        float g = bne[o], bb = bne[1024 + o], m = bne[2048 + o], vv = bne[3072 + o];
        float scale = g / sqrtf(vv + EPSB);
        sa[tid] = scale; sc[tid] = bb - m * scale;
    }
    f32x4 acc[4][4] = {};
    const ushort_t* cT = catT + (size_t)b * N_PTS * 512;
    int r0 = tid >> 2, s = tid & 3;
    for (int k0 = 0; k0 < 512; k0 += 32) {
        __syncthreads();
        for (int h = 0; h < 2; h++) {
            int r = r0 + h * 64;
            *(short8*)&sA[r * 40 + s * 8] = *(const short8*)(weh + (size_t)(o0 + r) * 512 + k0 + s * 8);
            *(short8*)&sB[r * 40 + s * 8] = *(const short8*)(cT  + (size_t)(n0 + r) * 512 + k0 + s * 8);
        }
        __syncthreads();
        short8 af[4], bfr[4];
        for (int mi = 0; mi < 4; mi++)
            af[mi] = *(const short8*)&sA[(mblk * 64 + mi * 16 + lr) * 40 + q * 8];
        for (int ni = 0; ni < 4; ni++)
            bfr[ni] = *(const short8*)&sB[(nblk * 64 + ni * 16 + lr) * 40 + q * 8];
        for (int mi = 0; mi < 4; mi++)
            for (int ni = 0; ni < 4; ni++)
                acc[mi][ni] = __builtin_amdgcn_mfma_f32_16x16x32_bf16(af[mi], bfr[ni], acc[mi][ni], 0, 0, 0);
    }
    for (int mi = 0; mi < 4; mi++) {
        for (int r = 0; r < 4; r++) {
            int row = mblk * 64 + mi * 16 + q * 4 + r;
            float a = sa[row], c = sc[row];
            float mx = -INFINITY, sm = 0.f;
            for (int ni = 0; ni < 4; ni++) {
                float y = lrelu(acc[mi][ni][r] * a + c);
                mx = fmaxf(mx, y); sm += y;
            }
            for (int msk = 1; msk < 16; msk <<= 1) {
                mx = fmaxf(mx, __shfl_xor(mx, msk, 16));
                sm += __shfl_xor(sm, msk, 16);
            }
            if (lr == 0) { redmax[row][nblk] = mx; redsum[row][nblk] = sm; }
        }
    }
    __syncthreads();
    if (tid < 128) {
        float mx = fmaxf(redmax[tid][0], redmax[tid][1]);
        float sm = redsum[tid][0] + redsum[tid][1];
        int o = o0 + tid;
        pmax[((size_t)(b * 1024 + o)) * 8 + nt] = mx;
        psum[((size_t)(b * 1024 + o)) * 8 + nt] = sm;
    }
}

__global__ void pool_reduce_kernel(const float* __restrict__ pmax, const float* __restrict__ psum,
                                   float* __restrict__ h0) {
    int g = blockIdx.x * 256 + threadIdx.x;  // b*1024 + o
    int b = g >> 10, o = g & 1023;
    float mx = -INFINITY, sm = 0.f;
    for (int t = 0; t < 8; t++) { mx = fmaxf(mx, pmax[g * 8 + t]); sm += psum[g * 8 + t]; }
    h0[(size_t)b * 2048 + o] = mx;
    h0[(size_t)b * 2048 + 1024 + o] = sm * (1.0f / 1024.0f);
}

// ---------------- FC: one wave per output ----------------
__global__ void fc_kernel(const float* __restrict__ in, const float* __restrict__ w,
                          const float* __restrict__ bnp, const float* __restrict__ bias,
                          float* __restrict__ out, int Cin, int Cout, int mode) {
    int blk = blockIdx.x;  // b*Cout + o
    int b = blk / Cout, o = blk % Cout;
    int lane = threadIdx.x;
    const float* inb = in + (size_t)b * Cin;
    const float* wo = w + (size_t)o * Cin;
    float acc = 0.f;
    for (int c = lane; c < Cin; c += 64) acc += inb[c] * wo[c];
    for (int s = 32; s > 0; s >>= 1) acc += __shfl_down(acc, s, 64);
    if (lane == 0) {
        float y = acc;
        if (mode == 0) {
            float g = bnp[o], bb = bnp[Cout + o], m = bnp[2 * Cout + o], vv = bnp[3 * Cout + o];
            y = lrelu((y - m) * (g / sqrtf(vv + EPSB)) + bb);
        } else {
            y += bias[o];
        }
        out[(size_t)b * Cout + o] = y;
    }
}

extern "C" void kernel_launch(void* const* d_in, const int* in_sizes, int n_in,
                              void* d_out, int out_size, void* d_ws, size_t ws_size,
                              hipStream_t stream) {
    const float* x    = (const float*)d_in[0];
    const float* w0   = (const float*)d_in[1];
    const float* w1   = (const float*)d_in[2];
    const float* w2   = (const float*)d_in[3];
    const float* w3   = (const float*)d_in[4];
    const float* bn0  = (const float*)d_in[5];
    const float* bn1  = (const float*)d_in[6];
    const float* bn2  = (const float*)d_in[7];
    const float* bn3  = (const float*)d_in[8];
    const float* we   = (const float*)d_in[9];
    const float* bne  = (const float*)d_in[10];
    const float* wf0  = (const float*)d_in[11];
    const float* bnf0 = (const float*)d_in[12];
    const float* wf1  = (const float*)d_in[13];
    const float* bnf1 = (const float*)d_in[14];
    const float* wfin = (const float*)d_in[15];
    const float* bfin = (const float*)d_in[16];

    float* ws = (float*)d_ws;
    size_t off = 0;
    float* cat  = ws + off; off += (size_t)BATCH * 512 * N_PTS;        // 16 MB
    float* U    = ws + off; off += (size_t)BATCH * N_PTS * N_PTS;      // 33.5 MB (pd | A+Bv union)
    float* pd   = U;
    float* A    = U;
    float* Bv   = U + (size_t)BATCH * 256 * N_PTS;
    float* xx   = ws + off; off += (size_t)BATCH * N_PTS;
    float* pmax = ws + off; off += (size_t)BATCH * N_PTS * 8;
    float* psum = ws + off; off += (size_t)BATCH * N_PTS * 8;
    float* h0   = ws + off; off += (size_t)BATCH * 2048;
    float* h1   = ws + off; off += (size_t)BATCH * 512;
    float* h2   = ws + off; off += (size_t)BATCH * 256;
    int*   idx  = (int*)(ws + off); off += (size_t)BATCH * N_PTS * KNN;
    ushort_t* weh  = (ushort_t*)(ws + off); off += (size_t)(1024 * 512) / 2;        // 1 MB
    ushort_t* catT = (ushort_t*)(ws + off); off += (size_t)BATCH * N_PTS * 512 / 2; // 8 MB
    float* wpt  = ws + off; off += (size_t)128 * 512;                   // 256 KB W' buffer

    const int CSTR = 512 * N_PTS;   // cat batch stride
    const dim3 pdGrid(8, 8, BATCH);
    const int  topkBlocks = BATCH * N_PTS / 4;

    // we -> bf16 (independent, run first)
    wconv_kernel<<<512, 256, 0, stream>>>(we, weh);

    // ---- block 0: input x (B,3,N), C=3 -> Cout=64, out ch [0,64)
    xx_kernel<<<32, 256, 0, stream>>>(x, xx, 3, 3 * N_PTS);
    pd_kernel<<<pdGrid, 256, 0, stream>>>(x, xx, pd, 3, 3 * N_PTS);
    topk_kernel<<<topkBlocks, 256, 0, stream>>>(pd, idx);
    wprep_kernel<<<(3 * 128 + 255) / 256, 256, 0, stream>>>(w0, wpt, 3, 64);
    abv_gemm<<<dim3(8, 1, BATCH), 256, 0, stream>>>(x, wpt, A, Bv, 3, 64, 3 * N_PTS);
    gmax_kernel<<<dim3(16, 16, BATCH), 256, 0, stream>>>(A, Bv, idx, bn0, cat, 64, CSTR);

    // ---- block 1: C=64 -> Cout=64, out ch [64,128)
    xx_kernel<<<32, 256, 0, stream>>>(cat, xx, 64, CSTR);
    pd_kernel<<<pdGrid, 256, 0, stream>>>(cat, xx, pd, 64, CSTR);
    topk_kernel<<<topkBlocks, 256, 0, stream>>>(pd, idx);
    wprep_kernel<<<(64 * 128 + 255) / 256, 256, 0, stream>>>(w1, wpt, 64, 64);
    abv_gemm<<<dim3(8, 1, BATCH), 256, 0, stream>>>(cat, wpt, A, Bv, 64, 64, CSTR);
    gmax_kernel<<<dim3(16, 16, BATCH), 256, 0, stream>>>(A, Bv, idx, bn1, cat + 64 * N_PTS, 64, CSTR);

    // ---- block 2: C=64 -> Cout=128, out ch [128,256)
    xx_kernel<<<32, 256, 0, stream>>>(cat + 64 * N_PTS, xx, 64, CSTR);
    pd_kernel<<<pdGrid, 256, 0, stream>>>(cat + 64 * N_PTS, xx, pd, 64, CSTR);
    topk_kernel<<<topkBlocks, 256, 0, stream>>>(pd, idx);
    wprep_kernel<<<(64 * 256 + 255) / 256, 256, 0, stream>>>(w2, wpt, 64, 128);
    abv_gemm<<<dim3(8, 2, BATCH), 256, 0, stream>>>(cat + 64 * N_PTS, wpt, A, Bv, 64, 128, CSTR);
    gmax_kernel<<<dim3(16, 32, BATCH), 256, 0, stream>>>(A, Bv, idx, bn2, cat + 128 * N_PTS, 128, CSTR);

    // ---- block 3: C=128 -> Cout=256, out ch [256,512)
    xx_kernel<<<32, 256, 0, stream>>>(cat + 128 * N_PTS, xx, 128, CSTR);
    pd_kernel<<<pdGrid, 256, 0, stream>>>(cat + 128 * N_PTS, xx, pd, 128, CSTR);
    topk_kernel<<<topkBlocks, 256, 0, stream>>>(pd, idx);
    wprep_kernel<<<(128 * 512 + 255) / 256, 256, 0, stream>>>(w3, wpt, 128, 256);
    abv_gemm<<<dim3(8, 4, BATCH), 256, 0, stream>>>(cat + 128 * N_PTS, wpt, A, Bv, 128, 256, CSTR);
    gmax_kernel<<<dim3(16, 64, BATCH), 256, 0, stream>>>(A, Bv, idx, bn3, cat + 256 * N_PTS, 256, CSTR);

    // ---- cat -> bf16 transposed, then MFMA embedding + pooling
    catT_kernel<<<dim3(16, 8, BATCH), 256, 0, stream>>>(cat, catT);
    gemm6_mfma<<<dim3(8, 8, BATCH), 256, 0, stream>>>(weh, catT, bne, pmax, psum);
    pool_reduce_kernel<<<32, 256, 0, stream>>>(pmax, psum, h0);

    // ---- FC head
    fc_kernel<<<BATCH * 512, 64, 0, stream>>>(h0, wf0, bnf0, nullptr, h1, 2048, 512, 0);
    fc_kernel<<<BATCH * 256, 64, 0, stream>>>(h1, wf1, bnf1, nullptr, h2, 512, 256, 0);
    fc_kernel<<<BATCH * 64, 64, 0, stream>>>(h2, wfin, nullptr, bfin, (float*)d_out, 256, 64, 1);
}

// Round 7
// 331.129 us; speedup vs baseline: 3.6807x; 1.4674x over previous
//
#include <hip/hip_runtime.h>
#include <math.h>

#define N_PTS 1024
#define BATCH 8
#define KNN 20
#define EPSB 1e-5f
#define SLOPE 0.2f

typedef __attribute__((ext_vector_type(8))) short short8;
typedef __attribute__((ext_vector_type(4))) float f32x4;
typedef unsigned short ushort_t;
typedef unsigned long long u64;

__device__ __forceinline__ float lrelu(float y) { return y > 0.f ? y : SLOPE * y; }

__device__ __forceinline__ ushort_t f2bf(float f) {
    union { float f; unsigned u; } v; v.f = f;
    unsigned r = v.u + 0x7FFF + ((v.u >> 16) & 1);   // RNE
    return (ushort_t)(r >> 16);
}

// ---------------- fused weight prep: we->bf16 + 4x W' transforms ----------------
__device__ __forceinline__ void wprep_one(const float* __restrict__ w, float* __restrict__ wpt,
                                          int C, int Cout, int g) {
    int M2 = 2 * Cout;
    if (g >= C * M2) return;
    int c = g / M2, m = g - c * M2;
    float v;
    if (m < Cout) v = w[(size_t)m * 2 * C + c];
    else { int o = m - Cout; v = w[(size_t)o * 2 * C + C + c] - w[(size_t)o * 2 * C + c]; }
    wpt[(size_t)c * M2 + m] = v;
}

__global__ void prep_kernel(const float* __restrict__ we, ushort_t* __restrict__ weh,
                            const float* __restrict__ w0, float* __restrict__ wpt0,
                            const float* __restrict__ w1, float* __restrict__ wpt1,
                            const float* __restrict__ w2, float* __restrict__ wpt2,
                            const float* __restrict__ w3, float* __restrict__ wpt3) {
    int bx = blockIdx.x, tid = threadIdx.x;
    if (bx < 512) {
        int g = bx * 256 + tid;               // 131072 float4 of we
        float4 v = ((const float4*)we)[g];
        ushort4 o;
        o.x = f2bf(v.x); o.y = f2bf(v.y); o.z = f2bf(v.z); o.w = f2bf(v.w);
        ((ushort4*)weh)[g] = o;
    } else if (bx < 514) {
        wprep_one(w0, wpt0, 3, 64, (bx - 512) * 256 + tid);
    } else if (bx < 546) {
        wprep_one(w1, wpt1, 64, 64, (bx - 514) * 256 + tid);
    } else if (bx < 610) {
        wprep_one(w2, wpt2, 64, 128, (bx - 546) * 256 + tid);
    } else {
        wprep_one(w3, wpt3, 128, 256, (bx - 610) * 256 + tid);
    }
}

// ---------------- fused pd + abv (grid.x partition; xx computed inline) ----------------
// bx < 8 : pd tile  (m0 = bx*128)      pd[b,n,m] = 2*dot - xx[n] - xx[m]
// bx >= 8: abv tile (m0 = (bx-8)*128)  [A;Bv] = W' * x
// NOTE: pd and A/Bv MUST be disjoint buffers — both are written concurrently here.
__global__ void __launch_bounds__(256)
pdabv_kernel(const float* __restrict__ x, const float* __restrict__ wpt,
             float* __restrict__ pd, float* __restrict__ A, float* __restrict__ Bv,
             int C, int Cout, int bstride) {
    int b = blockIdx.z;
    int nt = blockIdx.y;
    int bx = blockIdx.x;
    int tid = threadIdx.x;
    int tx = tid & 15, ty = tid >> 4;
    int n0 = nt * 128;
    __shared__ float sU0[16][128];
    __shared__ float sU1[16][128];
    __shared__ float sXX[256];
    const float* xb = x + (size_t)b * bstride;
    float acc[8][8] = {};
    if (bx < 8) {
        // ---- pd path ----
        int m0 = bx * 128;
        float xxa = 0.f;
        for (int c0 = 0; c0 < C; c0 += 16) {
            for (int q = 0; q < 2; q++) {
                int f = q * 256 + tid;
                int r = f >> 5, col = (f & 31) * 4;
                int c = c0 + r;
                float4 vn = {0.f, 0.f, 0.f, 0.f}, vm = {0.f, 0.f, 0.f, 0.f};
                if (c < C) {
                    vn = *(const float4*)&xb[(size_t)c * N_PTS + n0 + col];
                    vm = *(const float4*)&xb[(size_t)c * N_PTS + m0 + col];
                }
                *(float4*)&sU0[r][col] = vn;
                *(float4*)&sU1[r][col] = vm;
            }
            __syncthreads();
            if (tid < 128) {
                for (int k = 0; k < 16; k++) { float v = sU0[k][tid]; xxa += v * v; }
            } else {
                int u = tid - 128;
                for (int k = 0; k < 16; k++) { float v = sU1[k][u]; xxa += v * v; }
            }
            for (int k = 0; k < 16; k++) {
                float4 a0 = *(const float4*)&sU0[k][ty * 4];
                float4 a1 = *(const float4*)&sU0[k][64 + ty * 4];
                float4 b0 = *(const float4*)&sU1[k][tx * 4];
                float4 b1 = *(const float4*)&sU1[k][64 + tx * 4];
                float av[8] = {a0.x, a0.y, a0.z, a0.w, a1.x, a1.y, a1.z, a1.w};
                float bw[8] = {b0.x, b0.y, b0.z, b0.w, b1.x, b1.y, b1.z, b1.w};
                for (int i = 0; i < 8; i++)
                    for (int j = 0; j < 8; j++) acc[i][j] += av[i] * bw[j];
            }
            __syncthreads();
        }
        sXX[tid] = xxa;
        __syncthreads();
        float xnv[8], xmv[8];
        for (int i = 0; i < 8; i++) xnv[i] = sXX[(i >> 2) * 64 + ty * 4 + (i & 3)];
        for (int j = 0; j < 8; j++) xmv[j] = sXX[128 + (j >> 2) * 64 + tx * 4 + (j & 3)];
        for (int i = 0; i < 8; i++) {
            int n = n0 + (i >> 2) * 64 + ty * 4 + (i & 3);
            float* prow = pd + ((size_t)(b * N_PTS + n)) * N_PTS;
            for (int jh = 0; jh < 2; jh++) {
                float4 o;
                o.x = 2.f * acc[i][jh * 4 + 0] - xnv[i] - xmv[jh * 4 + 0];
                o.y = 2.f * acc[i][jh * 4 + 1] - xnv[i] - xmv[jh * 4 + 1];
                o.z = 2.f * acc[i][jh * 4 + 2] - xnv[i] - xmv[jh * 4 + 2];
                o.w = 2.f * acc[i][jh * 4 + 3] - xnv[i] - xmv[jh * 4 + 3];
                *(float4*)&prow[m0 + jh * 64 + tx * 4] = o;
            }
        }
    } else {
        // ---- abv path ----
        int m0 = (bx - 8) * 128;
        int M2 = 2 * Cout;
        for (int c0 = 0; c0 < C; c0 += 16) {
            for (int q = 0; q < 2; q++) {
                int f = q * 256 + tid;
                int r = f >> 5, col = (f & 31) * 4;
                int c = c0 + r;
                float4 vw = {0.f, 0.f, 0.f, 0.f}, vx = {0.f, 0.f, 0.f, 0.f};
                if (c < C) {
                    vw = *(const float4*)&wpt[(size_t)c * M2 + m0 + col];
                    vx = *(const float4*)&xb[(size_t)c * N_PTS + n0 + col];
                }
                *(float4*)&sU0[r][col] = vw;
                *(float4*)&sU1[r][col] = vx;
            }
            __syncthreads();
            for (int k = 0; k < 16; k++) {
                float4 a0 = *(const float4*)&sU0[k][ty * 4];
                float4 a1 = *(const float4*)&sU0[k][64 + ty * 4];
                float4 b0 = *(const float4*)&sU1[k][tx * 4];
                float4 b1 = *(const float4*)&sU1[k][64 + tx * 4];
                float av[8] = {a0.x, a0.y, a0.z, a0.w, a1.x, a1.y, a1.z, a1.w};
                float bw[8] = {b0.x, b0.y, b0.z, b0.w, b1.x, b1.y, b1.z, b1.w};
                for (int i = 0; i < 8; i++)
                    for (int j = 0; j < 8; j++) acc[i][j] += av[i] * bw[j];
            }
            __syncthreads();
        }
        for (int i = 0; i < 8; i++) {
            int rowm = m0 + (i >> 2) * 64 + ty * 4 + (i & 3);
            float* dst = (rowm < Cout) ? (A + ((size_t)b * Cout + rowm) * N_PTS)
                                       : (Bv + ((size_t)b * Cout + rowm - Cout) * N_PTS);
            for (int jh = 0; jh < 2; jh++) {
                float4 o;
                o.x = acc[i][jh * 4 + 0];
                o.y = acc[i][jh * 4 + 1];
                o.z = acc[i][jh * 4 + 2];
                o.w = acc[i][jh * 4 + 3];
                *(float4*)&dst[n0 + jh * 64 + tx * 4] = o;
            }
        }
    }
}

// ---------------- top-20 per row: threshold-compact + bitonic select ----------------
__global__ void __launch_bounds__(256)
topk_kernel(const float* __restrict__ pd, int* __restrict__ idx) {
    int wid = threadIdx.x >> 6;
    int row = blockIdx.x * 4 + wid;          // row = b*N + n
    int lane = threadIdx.x & 63;
    __shared__ u64 Sk[4][64];
    const float* p = pd + (size_t)row * N_PTS;
    float v[16];
    for (int q = 0; q < 4; q++) {
        float4 t = *(const float4*)&p[lane * 16 + q * 4];
        v[q * 4 + 0] = t.x; v[q * 4 + 1] = t.y; v[q * 4 + 2] = t.z; v[q * 4 + 3] = t.w;
    }
    float lmax = v[0];
    #pragma unroll
    for (int j = 1; j < 16; j++) lmax = fmaxf(lmax, v[j]);
    float s = lmax;
    #pragma unroll
    for (int k = 2; k <= 64; k <<= 1) {
        #pragma unroll
        for (int j = k >> 1; j > 0; j >>= 1) {
            float o = __shfl_xor(s, j, 64);
            bool takeMin = (((lane & k) == 0) == ((lane & j) == 0));
            float mn = fminf(s, o), mx = fmaxf(s, o);
            s = takeMin ? mn : mx;
        }
    }
    float tp = __shfl(s, 44, 64);            // 20th largest lane-max
    unsigned hm = 0;
    #pragma unroll
    for (int j = 0; j < 16; j++) hm |= (v[j] >= tp ? 1u : 0u) << j;
    int cnt = __popc(hm);
    int incl = cnt;
    #pragma unroll
    for (int d = 1; d < 64; d <<= 1) {
        int o = __shfl_up(incl, d, 64);
        if (lane >= d) incl += o;
    }
    int total = __shfl(incl, 63, 64);
    int pos = incl - cnt;
    if (total <= 64) {
        #pragma unroll
        for (int j = 0; j < 16; j++) {
            if (hm & (1u << j)) {
                unsigned u = __float_as_uint(v[j]);
                unsigned msk = ((unsigned)((int)u >> 31)) | 0x80000000u;
                Sk[wid][pos] = ((u64)(u ^ msk) << 32) | (unsigned)(1023 - (lane * 16 + j));
                pos++;
            }
        }
        u64 key = (lane < total) ? Sk[wid][lane] : 0ull;
        #pragma unroll
        for (int k = 2; k <= 64; k <<= 1) {
            #pragma unroll
            for (int j = k >> 1; j > 0; j >>= 1) {
                u64 o = __shfl_xor(key, j, 64);
                bool takeMin = (((lane & k) == 0) == ((lane & j) == 0));
                bool sgt = key > o;
                key = (sgt != takeMin) ? key : o;
            }
        }
        if (lane >= 44) {
            int m = 1023 - (int)(unsigned)(key & 0xFFFFFFFFu);
            idx[row * KNN + (63 - lane)] = m;
        }
    } else {
        for (int kk = 0; kk < KNN; kk++) {
            float bv = v[0]; int bj = 0;
            #pragma unroll
            for (int j = 1; j < 16; j++) if (v[j] > bv) { bv = v[j]; bj = j; }
            int bi = lane * 16 + bj;
            for (int d = 32; d > 0; d >>= 1) {
                float ov = __shfl_down(bv, d, 64);
                int oi = __shfl_down(bi, d, 64);
                if (ov > bv || (ov == bv && oi < bi)) { bv = ov; bi = oi; }
            }
            bi = __shfl(bi, 0, 64);
            if ((bi >> 4) == lane) {
                #pragma unroll
                for (int j = 0; j < 16; j++) if (j == (bi & 15)) v[j] = -INFINITY;
            }
            if (lane == 0) idx[row * KNN + kk] = bi;
        }
    }
}

// ---------------- gmax: LDS-staged gather-max + BN + lrelu ----------------
__global__ void __launch_bounds__(256)
gmax_kernel(const float* __restrict__ A, const float* __restrict__ Bv,
            const int* __restrict__ idx, const float* __restrict__ bnp,
            float* __restrict__ out, int Cout, int outStrideB) {
    int b = blockIdx.z;
    int n0 = blockIdx.x * 64;
    int o0 = blockIdx.y * 4;
    int tid = threadIdx.x;
    __shared__ int sidx[64 * 21];
    __shared__ float sA[4][N_PTS];
    for (int t = tid; t < 64 * KNN; t += 256) {
        int nl = t / KNN, k = t - nl * KNN;
        sidx[nl * 21 + k] = idx[(b * N_PTS + n0) * KNN + t];
    }
    const float* Abase = A + ((size_t)b * Cout + o0) * N_PTS;
    for (int q = 0; q < 4; q++) {
        int f = q * 256 + tid;                 // 1024 float4
        int r = f >> 8, c4 = (f & 255) * 4;
        *(float4*)&sA[r][c4] = *(const float4*)&Abase[(size_t)r * N_PTS + c4];
    }
    __syncthreads();
    int nl = tid & 63, ol = tid >> 6;
    float best = -INFINITY;
    #pragma unroll
    for (int k = 0; k < KNN; k++) {
        int j = sidx[nl * 21 + k];
        best = fmaxf(best, sA[ol][j]);
    }
    int o = o0 + ol;
    int n = n0 + nl;
    float pre = best + Bv[((size_t)b * Cout + o) * N_PTS + n];
    float g = bnp[o], bb = bnp[Cout + o], m = bnp[2 * Cout + o], vv = bnp[3 * Cout + o];
    float scale = g / sqrtf(vv + EPSB);
    out[(size_t)b * outStrideB + (size_t)o * N_PTS + n] = lrelu((pre - m) * scale + bb);
}

// ---------------- cat fp32 [b][c][n] -> catT bf16 [b][n][c] ----------------
__global__ void catT_kernel(const float* __restrict__ cat, ushort_t* __restrict__ catT) {
    int b = blockIdx.z, ct = blockIdx.y, nt = blockIdx.x;
    int tid = threadIdx.x;
    __shared__ float tile[64][65];
    const float* cb = cat + (size_t)b * 512 * N_PTS;
    for (int q = 0; q < 16; q++) {
        int e = q * 256 + tid;
        int c = e >> 6, n = e & 63;
        tile[c][n] = cb[(size_t)(ct * 64 + c) * N_PTS + nt * 64 + n];
    }
    __syncthreads();
    for (int q = 0; q < 16; q++) {
        int e = q * 256 + tid;
        int n = e >> 6, c = e & 63;
        catT[((size_t)b * N_PTS + nt * 64 + n) * 512 + ct * 64 + c] = f2bf(tile[c][n]);
    }
}

// ---------------- embedding GEMM (bf16 MFMA) + bn + lrelu + fused max/sum ----------------
__global__ void __launch_bounds__(256)
gemm6_mfma(const ushort_t* __restrict__ weh, const ushort_t* __restrict__ catT,
           const float* __restrict__ bne,
           float* __restrict__ pmax, float* __restrict__ psum) {
    int b = blockIdx.z, ot = blockIdx.y, nt = blockIdx.x;
    int tid = threadIdx.x;
    int w = tid >> 6, lane = tid & 63, q = lane >> 4, lr = lane & 15;
    int mblk = w >> 1, nblk = w & 1;
    __shared__ __align__(16) ushort_t sA[128 * 40];
    __shared__ __align__(16) ushort_t sB[128 * 40];
    __shared__ float sa[128], sc[128];
    __shared__ float redmax[128][2], redsum[128][2];
    int o0 = ot * 128, n0 = nt * 128;
    if (tid < 128) {
        int o = o0 + tid;
        float g = bne[o], bb = bne[1024 + o], m = bne[2048 + o], vv = bne[3072 + o];
        float scale = g / sqrtf(vv + EPSB);
        sa[tid] = scale; sc[tid] = bb - m * scale;
    }
    f32x4 acc[4][4] = {};
    const ushort_t* cT = catT + (size_t)b * N_PTS * 512;
    int r0 = tid >> 2, s = tid & 3;
    for (int k0 = 0; k0 < 512; k0 += 32) {
        __syncthreads();
        for (int h = 0; h < 2; h++) {
            int r = r0 + h * 64;
            *(short8*)&sA[r * 40 + s * 8] = *(const short8*)(weh + (size_t)(o0 + r) * 512 + k0 + s * 8);
            *(short8*)&sB[r * 40 + s * 8] = *(const short8*)(cT  + (size_t)(n0 + r) * 512 + k0 + s * 8);
        }
        __syncthreads();
        short8 af[4], bfr[4];
        for (int mi = 0; mi < 4; mi++)
            af[mi] = *(const short8*)&sA[(mblk * 64 + mi * 16 + lr) * 40 + q * 8];
        for (int ni = 0; ni < 4; ni++)
            bfr[ni] = *(const short8*)&sB[(nblk * 64 + ni * 16 + lr) * 40 + q * 8];
        for (int mi = 0; mi < 4; mi++)
            for (int ni = 0; ni < 4; ni++)
                acc[mi][ni] = __builtin_amdgcn_mfma_f32_16x16x32_bf16(af[mi], bfr[ni], acc[mi][ni], 0, 0, 0);
    }
    for (int mi = 0; mi < 4; mi++) {
        for (int r = 0; r < 4; r++) {
            int row = mblk * 64 + mi * 16 + q * 4 + r;
            float a = sa[row], c = sc[row];
            float mx = -INFINITY, sm = 0.f;
            for (int ni = 0; ni < 4; ni++) {
                float y = lrelu(acc[mi][ni][r] * a + c);
                mx = fmaxf(mx, y); sm += y;
            }
            for (int msk = 1; msk < 16; msk <<= 1) {
                mx = fmaxf(mx, __shfl_xor(mx, msk, 16));
                sm += __shfl_xor(sm, msk, 16);
            }
            if (lr == 0) { redmax[row][nblk] = mx; redsum[row][nblk] = sm; }
        }
    }
    __syncthreads();
    if (tid < 128) {
        float mx = fmaxf(redmax[tid][0], redmax[tid][1]);
        float sm = redsum[tid][0] + redsum[tid][1];
        int o = o0 + tid;
        pmax[((size_t)(b * 1024 + o)) * 8 + nt] = mx;
        psum[((size_t)(b * 1024 + o)) * 8 + nt] = sm;
    }
}

__global__ void pool_reduce_kernel(const float* __restrict__ pmax, const float* __restrict__ psum,
                                   float* __restrict__ h0) {
    int g = blockIdx.x * 256 + threadIdx.x;  // b*1024 + o
    int b = g >> 10, o = g & 1023;
    float mx = -INFINITY, sm = 0.f;
    for (int t = 0; t < 8; t++) { mx = fmaxf(mx, pmax[g * 8 + t]); sm += psum[g * 8 + t]; }
    h0[(size_t)b * 2048 + o] = mx;
    h0[(size_t)b * 2048 + 1024 + o] = sm * (1.0f / 1024.0f);
}

// ---------------- FC: one wave per output ----------------
__global__ void fc_kernel(const float* __restrict__ in, const float* __restrict__ w,
                          const float* __restrict__ bnp, const float* __restrict__ bias,
                          float* __restrict__ out, int Cin, int Cout, int mode) {
    int blk = blockIdx.x;  // b*Cout + o
    int b = blk / Cout, o = blk % Cout;
    int lane = threadIdx.x;
    const float* inb = in + (size_t)b * Cin;
    const float* wo = w + (size_t)o * Cin;
    float acc = 0.f;
    for (int c = lane; c < Cin; c += 64) acc += inb[c] * wo[c];
    for (int s = 32; s > 0; s >>= 1) acc += __shfl_down(acc, s, 64);
    if (lane == 0) {
        float y = acc;
        if (mode == 0) {
            float g = bnp[o], bb = bnp[Cout + o], m = bnp[2 * Cout + o], vv = bnp[3 * Cout + o];
            y = lrelu((y - m) * (g / sqrtf(vv + EPSB)) + bb);
        } else {
            y += bias[o];
        }
        out[(size_t)b * Cout + o] = y;
    }
}

extern "C" void kernel_launch(void* const* d_in, const int* in_sizes, int n_in,
                              void* d_out, int out_size, void* d_ws, size_t ws_size,
                              hipStream_t stream) {
    const float* x    = (const float*)d_in[0];
    const float* w0   = (const float*)d_in[1];
    const float* w1   = (const float*)d_in[2];
    const float* w2   = (const float*)d_in[3];
    const float* w3   = (const float*)d_in[4];
    const float* bn0  = (const float*)d_in[5];
    const float* bn1  = (const float*)d_in[6];
    const float* bn2  = (const float*)d_in[7];
    const float* bn3  = (const float*)d_in[8];
    const float* we   = (const float*)d_in[9];
    const float* bne  = (const float*)d_in[10];
    const float* wf0  = (const float*)d_in[11];
    const float* bnf0 = (const float*)d_in[12];
    const float* wf1  = (const float*)d_in[13];
    const float* bnf1 = (const float*)d_in[14];
    const float* wfin = (const float*)d_in[15];
    const float* bfin = (const float*)d_in[16];

    float* ws = (float*)d_ws;
    size_t off = 0;
    float* cat  = ws + off; off += (size_t)BATCH * 512 * N_PTS;        // 16 MB
    float* pd   = ws + off; off += (size_t)BATCH * N_PTS * N_PTS;      // 33.5 MB
    float* A    = ws + off; off += (size_t)BATCH * 256 * N_PTS;        // 8 MB  (disjoint from pd!)
    float* Bv   = ws + off; off += (size_t)BATCH * 256 * N_PTS;        // 8 MB
    float* pmax = ws + off; off += (size_t)BATCH * N_PTS * 8;
    float* psum = ws + off; off += (size_t)BATCH * N_PTS * 8;
    float* h0   = ws + off; off += (size_t)BATCH * 2048;
    float* h1   = ws + off; off += (size_t)BATCH * 512;
    float* h2   = ws + off; off += (size_t)BATCH * 256;
    int*   idx  = (int*)(ws + off); off += (size_t)BATCH * N_PTS * KNN;
    ushort_t* weh  = (ushort_t*)(ws + off); off += (size_t)(1024 * 512) / 2;        // 1 MB
    ushort_t* catT = (ushort_t*)(ws + off); off += (size_t)BATCH * N_PTS * 512 / 2; // 8 MB
    float* wpt0 = ws + off; off += 3 * 128;
    float* wpt1 = ws + off; off += 64 * 128;
    float* wpt2 = ws + off; off += 64 * 256;
    float* wpt3 = ws + off; off += 128 * 512;

    const int CSTR = 512 * N_PTS;   // cat batch stride
    const int topkBlocks = BATCH * N_PTS / 4;

    // ---- all weight prep in one launch
    prep_kernel<<<866, 256, 0, stream>>>(we, weh, w0, wpt0, w1, wpt1, w2, wpt2, w3, wpt3);

    // ---- block 0: input x (B,3,N), C=3 -> Cout=64, out ch [0,64)
    pdabv_kernel<<<dim3(9, 8, BATCH), 256, 0, stream>>>(x, wpt0, pd, A, Bv, 3, 64, 3 * N_PTS);
    topk_kernel<<<topkBlocks, 256, 0, stream>>>(pd, idx);
    gmax_kernel<<<dim3(16, 16, BATCH), 256, 0, stream>>>(A, Bv, idx, bn0, cat, 64, CSTR);

    // ---- block 1: C=64 -> Cout=64, out ch [64,128)
    pdabv_kernel<<<dim3(9, 8, BATCH), 256, 0, stream>>>(cat, wpt1, pd, A, Bv, 64, 64, CSTR);
    topk_kernel<<<topkBlocks, 256, 0, stream>>>(pd, idx);
    gmax_kernel<<<dim3(16, 16, BATCH), 256, 0, stream>>>(A, Bv, idx, bn1, cat + 64 * N_PTS, 64, CSTR);

    // ---- block 2: C=64 -> Cout=128, out ch [128,256)
    pdabv_kernel<<<dim3(10, 8, BATCH), 256, 0, stream>>>(cat + 64 * N_PTS, wpt2, pd, A, Bv, 64, 128, CSTR);
    topk_kernel<<<topkBlocks, 256, 0, stream>>>(pd, idx);
    gmax_kernel<<<dim3(16, 32, BATCH), 256, 0, stream>>>(A, Bv, idx, bn2, cat + 128 * N_PTS, 128, CSTR);

    // ---- block 3: C=128 -> Cout=256, out ch [256,512)
    pdabv_kernel<<<dim3(12, 8, BATCH), 256, 0, stream>>>(cat + 128 * N_PTS, wpt3, pd, A, Bv, 128, 256, CSTR);
    topk_kernel<<<topkBlocks, 256, 0, stream>>>(pd, idx);
    gmax_kernel<<<dim3(16, 64, BATCH), 256, 0, stream>>>(A, Bv, idx, bn3, cat + 256 * N_PTS, 256, CSTR);

    // ---- cat -> bf16 transposed, then MFMA embedding + pooling
    catT_kernel<<<dim3(16, 8, BATCH), 256, 0, stream>>>(cat, catT);
    gemm6_mfma<<<dim3(8, 8, BATCH), 256, 0, stream>>>(weh, catT, bne, pmax, psum);
    pool_reduce_kernel<<<32, 256, 0, stream>>>(pmax, psum, h0);

    // ---- FC head
    fc_kernel<<<BATCH * 512, 64, 0, stream>>>(h0, wf0, bnf0, nullptr, h1, 2048, 512, 0);
    fc_kernel<<<BATCH * 256, 64, 0, stream>>>(h1, wf1, bnf1, nullptr, h2, 512, 256, 0);
    fc_kernel<<<BATCH * 64, 64, 0, stream>>>(h2, wfin, nullptr, bfin, (float*)d_out, 256, 64, 1);
}